// Round 1
// baseline (231.696 us; speedup 1.0000x reference)
//
#include <hip/hip_runtime.h>
#include <hip/hip_bf16.h>

#define B_    4
#define C_    128
#define HW_   16384
#define K_    1024
// softmax runs in log2 domain: fold 128^-0.5 * log2(e) into the QK epilogue FMA
#define SC2_  0.12751734f
#define NEGL_ (-1.4427e7f)        // NEG * log2(e)
#define DTHR_ 8.0f                // defer-max threshold (log2 units): p <= 2^8

using bf16 = __hip_bfloat16;
typedef __bf16 b8v __attribute__((ext_vector_type(8)));
typedef __bf16 b4v __attribute__((ext_vector_type(4)));
typedef __bf16 b2v __attribute__((ext_vector_type(2)));
typedef float  f4v __attribute__((ext_vector_type(4)));

__device__ __forceinline__ b8v ldb8(const void* p) { return *(const b8v*)p; }

#define XSTRIDE 272   // 256 B row + 16 pad (b128 frag reads at bank floor)
#define KSTRIDE 272
#define VSTRIDE 144   // 128 B interleaved row + 16 pad; b128 reads at bank floor

// weight row (f32) -> bf16 fragment with BN scale folded, inline
__device__ __forceinline__ b8v ldw8(const float* wp, float sc) {
    const float4 a = *(const float4*)wp;
    const float4 c = *(const float4*)(wp + 4);
    b8v r;
    r[0] = (__bf16)(a.x * sc); r[1] = (__bf16)(a.y * sc);
    r[2] = (__bf16)(a.z * sc); r[3] = (__bf16)(a.w * sc);
    r[4] = (__bf16)(c.x * sc); r[5] = (__bf16)(c.y * sc);
    r[6] = (__bf16)(c.z * sc); r[7] = (__bf16)(c.w * sc);
    return r;
}

// ---------------------------------------------------------------------------
// prep: merged prep1 + kvproj.
//   blk [0,32)       : self-contained k/v projection blocks (own transpose,
//                      inline weight fold) -> kbuf [b][k][c], vbuf [b][c][k].
//                      Placed FIRST so they run concurrently with transposes.
//   blk [32,1056)    : query transpose  f32 [b][c][p] -> bf16 qt [b][p][c]
//   blk [1056,1504)  : mega weight prep (Wq1,Wq2,Wo,Wb: 114688 elems)
// ---------------------------------------------------------------------------
__global__ __launch_bounds__(256, 2) void prep_kernel(
    const float* __restrict__ query, const float* __restrict__ key, const float* __restrict__ val,
    const float* __restrict__ Wq1, const float* __restrict__ sq1,
    const float* __restrict__ Wq2, const float* __restrict__ sq2,
    const float* __restrict__ Wo,  const float* __restrict__ so,
    const float* __restrict__ Wb,  const float* __restrict__ sb,
    const float* __restrict__ Wk1, const float* __restrict__ sk1, const float* __restrict__ bk1,
    const float* __restrict__ Wk2, const float* __restrict__ sk2, const float* __restrict__ bk2,
    const float* __restrict__ Wv,  const float* __restrict__ sv_, const float* __restrict__ bv,
    bf16* __restrict__ qt, bf16* __restrict__ kbuf, bf16* __restrict__ vbuf,
    __bf16* __restrict__ Wq1p, __bf16* __restrict__ Wq2p,
    __bf16* __restrict__ Wop,  __bf16* __restrict__ Wbp)
{
    __shared__ __align__(16) char SM[69632];
    const int blk = blockIdx.x, t = threadIdx.x;

    if (blk < 32) {
        // ================= fused k/v projection =================
        const int b = blk >> 3, n0 = (blk & 7) * 128;
        const int w = t >> 6, lane = t & 63;
        const int pl = lane & 15, quad = lane >> 4;
        const int ob = 32 * w;
        const int plT = t & 63, cg = t >> 6;
        char*    Xs  = SM;                       // bf16 [128 pos][XSTRIDE]
        __bf16*  Ys  = (__bf16*)(SM + 34816);    // bf16 [128][136]
        float*   Tmp = (float*)(SM + 34816);     // f32 [64][129] (aliases Ys)

        // transpose a [128c][128p] f32 tile from src into Xs (bf16, [p][c])
        auto transpose_in = [&](const float* src) {
#pragma unroll
            for (int h = 0; h < 2; ++h) {
                const int p0 = n0 + h * 64;
#pragma unroll 4
                for (int i2 = 0; i2 < 32; ++i2) {
                    const int c = cg * 32 + i2;
                    Tmp[plT * 129 + c] = src[(size_t)(b * 128 + c) * K_ + p0 + plT];
                }
                __syncthreads();
#pragma unroll 4
                for (int it = 0; it < 16; ++it) {
                    const int p = it * 4 + cg;
                    b2v pk2;
                    pk2[0] = (__bf16)Tmp[p * 129 + 2 * plT];
                    pk2[1] = (__bf16)Tmp[p * 129 + 2 * plT + 1];
                    *(b2v*)(Xs + (h * 64 + p) * XSTRIDE + 4 * plT) = pk2;
                }
                __syncthreads();
            }
        };

        // ---- K projection (2 layers) ----
        transpose_in(key);
        b8v W1f[2][4], W2f[2][4];
#pragma unroll
        for (int mt = 0; mt < 2; ++mt)
#pragma unroll
            for (int s = 0; s < 4; ++s) {
                const int row = ob + mt * 16 + pl;
                W1f[mt][s] = ldw8(Wk1 + row * 128 + s * 32 + quad * 8, sk1[row]);
                W2f[mt][s] = ldw8(Wk2 + row * 128 + s * 32 + quad * 8, sk2[row]);
            }
        {
            f4v acc[2][8];
#pragma unroll
            for (int mt = 0; mt < 2; ++mt)
#pragma unroll
                for (int nt = 0; nt < 8; ++nt) acc[mt][nt] = (f4v){0.f, 0.f, 0.f, 0.f};
#pragma unroll
            for (int s = 0; s < 4; ++s) {
                b8v Bf[8];
#pragma unroll
                for (int nt = 0; nt < 8; ++nt)
                    Bf[nt] = ldb8(Xs + (nt * 16 + pl) * XSTRIDE + s * 64 + quad * 16);
#pragma unroll
                for (int mt = 0; mt < 2; ++mt)
#pragma unroll
                    for (int nt = 0; nt < 8; ++nt)
                        acc[mt][nt] = __builtin_amdgcn_mfma_f32_16x16x32_bf16(W1f[mt][s], Bf[nt], acc[mt][nt], 0, 0, 0);
            }
#pragma unroll
            for (int mt = 0; mt < 2; ++mt) {
                const float4 s4 = *(const float4*)(bk1 + ob + mt * 16 + quad * 4);
                const float shf[4] = {s4.x, s4.y, s4.z, s4.w};
#pragma unroll
                for (int nt = 0; nt < 8; ++nt) {
                    b4v y;
#pragma unroll
                    for (int r = 0; r < 4; ++r) y[r] = (__bf16)fmaxf(acc[mt][nt][r] + shf[r], 0.f);
                    *(b4v*)&Ys[(nt * 16 + pl) * 136 + ob + mt * 16 + quad * 4] = y;
                }
            }
        }
        __syncthreads();
        {
            f4v acc2[2][8];
#pragma unroll
            for (int mt = 0; mt < 2; ++mt)
#pragma unroll
                for (int nt = 0; nt < 8; ++nt) acc2[mt][nt] = (f4v){0.f, 0.f, 0.f, 0.f};
#pragma unroll
            for (int s = 0; s < 4; ++s) {
                b8v Bf[8];
#pragma unroll
                for (int nt = 0; nt < 8; ++nt)
                    Bf[nt] = *(const b8v*)&Ys[(nt * 16 + pl) * 136 + s * 32 + quad * 8];
#pragma unroll
                for (int mt = 0; mt < 2; ++mt)
#pragma unroll
                    for (int nt = 0; nt < 8; ++nt)
                        acc2[mt][nt] = __builtin_amdgcn_mfma_f32_16x16x32_bf16(W2f[mt][s], Bf[nt], acc2[mt][nt], 0, 0, 0);
            }
            bf16* kdst = kbuf + ((size_t)b * K_ + n0) * 128;
#pragma unroll
            for (int mt = 0; mt < 2; ++mt) {
                const float4 s4 = *(const float4*)(bk2 + ob + mt * 16 + quad * 4);
                const float shf[4] = {s4.x, s4.y, s4.z, s4.w};
#pragma unroll
                for (int nt = 0; nt < 8; ++nt) {
                    b4v y;
#pragma unroll
                    for (int r = 0; r < 4; ++r) y[r] = (__bf16)fmaxf(acc2[mt][nt][r] + shf[r], 0.f);
                    *(b4v*)(kdst + (size_t)(nt * 16 + pl) * 128 + ob + mt * 16 + quad * 4) = y;
                }
            }
        }
        __syncthreads();   // Ys reads done before val-transpose reuses Tmp

        // ---- V projection (1 layer) ----
        transpose_in(val);
        b8v Wvf[2][4];
#pragma unroll
        for (int mt = 0; mt < 2; ++mt)
#pragma unroll
            for (int s = 0; s < 4; ++s) {
                const int row = ob + mt * 16 + pl;
                Wvf[mt][s] = ldw8(Wv + row * 128 + s * 32 + quad * 8, sv_[row]);
            }
        {
            f4v acc[2][8];
#pragma unroll
            for (int mt = 0; mt < 2; ++mt)
#pragma unroll
                for (int nt = 0; nt < 8; ++nt) acc[mt][nt] = (f4v){0.f, 0.f, 0.f, 0.f};
#pragma unroll
            for (int s = 0; s < 4; ++s) {
                b8v Bf[8];
#pragma unroll
                for (int nt = 0; nt < 8; ++nt)
                    Bf[nt] = ldb8(Xs + (nt * 16 + pl) * XSTRIDE + s * 64 + quad * 16);
#pragma unroll
                for (int mt = 0; mt < 2; ++mt)
#pragma unroll
                    for (int nt = 0; nt < 8; ++nt)
                        acc[mt][nt] = __builtin_amdgcn_mfma_f32_16x16x32_bf16(Wvf[mt][s], Bf[nt], acc[mt][nt], 0, 0, 0);
            }
            bf16* vdst = vbuf + (size_t)b * 128 * K_;
#pragma unroll
            for (int mt = 0; mt < 2; ++mt) {
                const float4 s4 = *(const float4*)(bv + ob + mt * 16 + quad * 4);
                const float shf[4] = {s4.x, s4.y, s4.z, s4.w};
#pragma unroll
                for (int nt = 0; nt < 8; ++nt)
#pragma unroll
                    for (int r = 0; r < 4; ++r)
                        vdst[(size_t)(ob + mt * 16 + quad * 4 + r) * K_ + n0 + nt * 16 + pl]
                            = __float2bfloat16(fmaxf(acc[mt][nt][r] + shf[r], 0.f));
            }
        }
    } else if (blk < 1056) {
        // ================= query transpose =================
        float* Xs2 = (float*)SM;
        const int i = blk - 32;
        const int b = i >> 8, p0 = (i & 255) * 64;
        const int pl = t & 63, cg = t >> 6;
#pragma unroll 4
        for (int i2 = 0; i2 < 32; ++i2) {
            const int c = cg * 32 + i2;
            Xs2[pl * 129 + c] = query[(size_t)(b * 128 + c) * HW_ + p0 + pl];
        }
        __syncthreads();
#pragma unroll 4
        for (int it = 0; it < 16; ++it) {
            const int p = it * 4 + cg;
            b2v pk2;
            pk2[0] = (__bf16)Xs2[p * 129 + 2 * pl];
            pk2[1] = (__bf16)Xs2[p * 129 + 2 * pl + 1];
            *(b2v*)(qt + ((size_t)b * HW_ + p0 + p) * 128 + 2 * pl) = pk2;
        }
    } else {
        // ================= mega weight prep =================
        const int idx = (blk - 1056) * 256 + t;
        if (idx < 16384)      { Wq1p[idx] = (__bf16)(Wq1[idx] * sq1[idx >> 7]); }
        else if (idx < 32768) { const int i2 = idx - 16384; Wq2p[i2] = (__bf16)(Wq2[i2] * sq2[i2 >> 7]); }
        else if (idx < 49152) { const int i2 = idx - 32768; Wop[i2]  = (__bf16)(Wo[i2]  * so[i2 >> 7]); }
        else                  { const int i2 = idx - 49152; Wbp[i2]  = (__bf16)(Wb[i2]  * sb[i2 >> 8]); }
    }
}

// ---------------------------------------------------------------------------
// mega: qproj -> flash attention (dbuf K/V LDS, 1 raw barrier/chunk,
// log2-domain softmax with deferred rescale) -> out-project + bottleneck.
// One block = 128 queries, 256 threads, grid (HW/128, B). LDS 75776 B (2/CU).
// ---------------------------------------------------------------------------
__global__ __launch_bounds__(256, 2) void mega_kernel(
    const bf16* __restrict__ qt, const bf16* __restrict__ kbuf, const bf16* __restrict__ vbuf,
    const int* __restrict__ mask,
    const __bf16* __restrict__ Wq1p, const float* __restrict__ bq1,
    const __bf16* __restrict__ Wq2p, const float* __restrict__ bq2,
    const __bf16* __restrict__ Wop,  const float* __restrict__ bo,
    const __bf16* __restrict__ Wbp,  const float* __restrict__ bb,
    float* __restrict__ out)
{
    __shared__ __align__(16) char S[75776];

    const int t = threadIdx.x, w = t >> 6, lane = t & 63;
    const int pl = lane & 15, quad = lane >> 4;
    const int n0 = blockIdx.x * 128;
    const int b  = blockIdx.y;
    const int ob = 32 * w;

    char*   RA  = S;
    __bf16* RAh = (__bf16*)S;
    __bf16* RBh = (__bf16*)(S + 34816);
    char* xl = RA + (t >> 4) * XSTRIDE + (t & 15) * 16;

    // ================= phase 1: q projection (into LDS) =================
    {
        const char* qg = (const char*)(qt + ((size_t)b * HW_ + n0) * 128) + t * 16;
#pragma unroll
        for (int i = 0; i < 8; ++i)
            *(float4*)(xl + i * 16 * XSTRIDE) = *(const float4*)(qg + i * 4096);
    }
    {
        b8v W1f[2][4], W2f[2][4];
#pragma unroll
        for (int mt = 0; mt < 2; ++mt)
#pragma unroll
            for (int s = 0; s < 4; ++s) {
                W1f[mt][s] = ldb8(Wq1p + (ob + mt * 16 + pl) * 128 + s * 32 + quad * 8);
                W2f[mt][s] = ldb8(Wq2p + (ob + mt * 16 + pl) * 128 + s * 32 + quad * 8);
            }
        __syncthreads();                       // sync1: q-tile in RA

        f4v a1[2][8];
#pragma unroll
        for (int mt = 0; mt < 2; ++mt)
#pragma unroll
            for (int nt = 0; nt < 8; ++nt) a1[mt][nt] = (f4v){0.f, 0.f, 0.f, 0.f};
#pragma unroll
        for (int s = 0; s < 4; ++s) {
            b8v Bf[8];
#pragma unroll
            for (int nt = 0; nt < 8; ++nt)
                Bf[nt] = ldb8(RA + (nt * 16 + pl) * XSTRIDE + s * 64 + quad * 16);
#pragma unroll
            for (int mt = 0; mt < 2; ++mt)
#pragma unroll
                for (int nt = 0; nt < 8; ++nt)
                    a1[mt][nt] = __builtin_amdgcn_mfma_f32_16x16x32_bf16(W1f[mt][s], Bf[nt], a1[mt][nt], 0, 0, 0);
        }
#pragma unroll
        for (int mt = 0; mt < 2; ++mt) {
            const float4 s4 = *(const float4*)(bq1 + ob + mt * 16 + quad * 4);
            const float shf[4] = {s4.x, s4.y, s4.z, s4.w};
#pragma unroll
            for (int nt = 0; nt < 8; ++nt) {
                b4v y;
#pragma unroll
                for (int r = 0; r < 4; ++r) y[r] = (__bf16)fmaxf(a1[mt][nt][r] + shf[r], 0.f);
                *(b4v*)&RBh[(nt * 16 + pl) * 136 + ob + mt * 16 + quad * 4] = y;
            }
        }
        __syncthreads();                       // sync2: y1 in RB, RA reads done

        f4v a2[2][8];
#pragma unroll
        for (int mt = 0; mt < 2; ++mt)
#pragma unroll
            for (int nt = 0; nt < 8; ++nt) a2[mt][nt] = (f4v){0.f, 0.f, 0.f, 0.f};
#pragma unroll
        for (int s = 0; s < 4; ++s) {
            b8v Bf[8];
#pragma unroll
            for (int nt = 0; nt < 8; ++nt)
                Bf[nt] = *(const b8v*)&RBh[(nt * 16 + pl) * 136 + s * 32 + quad * 8];
#pragma unroll
            for (int mt = 0; mt < 2; ++mt)
#pragma unroll
                for (int nt = 0; nt < 8; ++nt)
                    a2[mt][nt] = __builtin_amdgcn_mfma_f32_16x16x32_bf16(W2f[mt][s], Bf[nt], a2[mt][nt], 0, 0, 0);
        }
#pragma unroll
        for (int mt = 0; mt < 2; ++mt) {
            const float4 s4 = *(const float4*)(bq2 + ob + mt * 16 + quad * 4);
            const float shf[4] = {s4.x, s4.y, s4.z, s4.w};
#pragma unroll
            for (int nt = 0; nt < 8; ++nt) {
                b4v y;
#pragma unroll
                for (int r = 0; r < 4; ++r) y[r] = (__bf16)fmaxf(a2[mt][nt][r] + shf[r], 0.f);
                *(b4v*)&RAh[(nt * 16 + pl) * 136 + ob + mt * 16 + quad * 4] = y;
            }
        }
        __syncthreads();                       // sync3: q[pos][c] in RA
    }

    // q fragments: wave w owns queries w*32..w*32+31 (2 tiles)
    b8v qf0[4], qf1[4];
#pragma unroll
    for (int s = 0; s < 4; ++s) {
        qf0[s] = ldb8(RA + (w * 32 + pl) * XSTRIDE + s * 64 + quad * 16);
        qf1[s] = ldb8(RA + (w * 32 + 16 + pl) * XSTRIDE + s * 64 + quad * 16);
    }
    __syncthreads();                           // sync4: qf read, RA free

    // ================= phase 2: attention =================
    float* bias = (float*)S;                   // 4096 B
    char* kt0 = S + 4096;                      // 2 x 17408
    char* kt1 = S + 21504;
    char* vt0 = S + 38912;                     // 2 x 18432
    char* vt1 = S + 57344;

    const bf16* kpt = kbuf + (size_t)b * K_ * 128;
    const bf16* vpt = vbuf + (size_t)b * 128 * K_;
    const char* kg = (const char*)kpt + t * 16;
    const char* vg = (const char*)(vpt + (size_t)(t >> 3) * K_) + (t & 7) * 16;
    const int klo = (t >> 4) * KSTRIDE + (t & 15) * 16;
    const int vj  = t & 7;
    // interleaved V row: slot q holds keys {q*4..q*4+3, 16+q*4..16+q*4+3}
    const int vlo = (t >> 3) * VSTRIDE + (vj >> 2) * 64 + (vj & 1) * 32 + ((vj >> 1) & 1) * 8;

    float4 kr[4], vr[4];

#define ISSUE_LOADS(chunk)                                            \
    { const char* kgn = kg + (chunk) * 16384;                         \
      const char* vgn = vg + (chunk) * 128;                           \
      kr[0] = *(const float4*)(kgn);                                  \
      kr[1] = *(const float4*)(kgn + 4096);                           \
      kr[2] = *(const float4*)(kgn + 8192);                           \
      kr[3] = *(const float4*)(kgn + 12288);                          \
      vr[0] = *(const float4*)(vgn);                                  \
      vr[1] = *(const float4*)(vgn + 65536);                          \
      vr[2] = *(const float4*)(vgn + 131072);                         \
      vr[3] = *(const float4*)(vgn + 196608); }

#define STAGE_WRITES(ktd, vtd)                                        \
    { char* klp = (ktd) + klo;                                        \
      *(float4*)(klp)                = kr[0];                         \
      *(float4*)(klp + 16 * KSTRIDE) = kr[1];                         \
      *(float4*)(klp + 32 * KSTRIDE) = kr[2];                         \
      *(float4*)(klp + 48 * KSTRIDE) = kr[3];                         \
      char* vlp = (vtd) + vlo;                                        \
      *(float2*)(vlp)                     = make_float2(vr[0].x, vr[0].y); \
      *(float2*)(vlp + 16)                = make_float2(vr[0].z, vr[0].w); \
      *(float2*)(vlp + 32 * VSTRIDE)      = make_float2(vr[1].x, vr[1].y); \
      *(float2*)(vlp + 32 * VSTRIDE + 16) = make_float2(vr[1].z, vr[1].w); \
      *(float2*)(vlp + 64 * VSTRIDE)      = make_float2(vr[2].x, vr[2].y); \
      *(float2*)(vlp + 64 * VSTRIDE + 16) = make_float2(vr[2].z, vr[2].w); \
      *(float2*)(vlp + 96 * VSTRIDE)      = make_float2(vr[3].x, vr[3].y); \
      *(float2*)(vlp + 96 * VSTRIDE + 16) = make_float2(vr[3].z, vr[3].w); }

#define RAW_BARRIER()                                                 \
    __builtin_amdgcn_sched_barrier(0);                                \
    asm volatile("s_waitcnt lgkmcnt(0)" ::: "memory");                \
    __builtin_amdgcn_s_barrier();                                     \
    __builtin_amdgcn_sched_barrier(0);

    ISSUE_LOADS(0)
    for (int i2 = t; i2 < K_; i2 += 256)
        bias[i2] = (mask[b * K_ + i2] != 0) ? 0.f : NEGL_;
    STAGE_WRITES(kt0, vt0)
    ISSUE_LOADS(1)

    f4v ac0[8], ac1[8];
#pragma unroll
    for (int i = 0; i < 8; ++i) { ac0[i] = (f4v){0.f,0.f,0.f,0.f}; ac1[i] = (f4v){0.f,0.f,0.f,0.f}; }
    float mrun0 = -3.0e38f, mrun1 = -3.0e38f, lrun0 = 0.f, lrun1 = 0.f;

    RAW_BARRIER()                              // chunk0 staged; chunk1 loads in flight

#pragma unroll 2
    for (int ch = 0; ch < 16; ++ch) {
        const char* ktc = (ch & 1) ? kt1 : kt0;
        const char* vtc = (ch & 1) ? vt1 : vt0;
        const int k0 = ch * 64;

        // ---- GEMM1: scores in log2 domain
        f4v sv0[4], sv1[4];
        __builtin_amdgcn_s_setprio(1);
#pragma unroll
        for (int kt = 0; kt < 4; ++kt) {
            f4v a0 = (f4v){0.f,0.f,0.f,0.f}, a1 = (f4v){0.f,0.f,0.f,0.f};
            const char* krow = ktc + (kt * 16 + pl) * KSTRIDE + quad * 16;
#pragma unroll
            for (int s = 0; s < 4; ++s) {
                const b8v kf = ldb8(krow + s * 64);
                a0 = __builtin_amdgcn_mfma_f32_16x16x32_bf16(kf, qf0[s], a0, 0, 0, 0);
                a1 = __builtin_amdgcn_mfma_f32_16x16x32_bf16(kf, qf1[s], a1, 0, 0, 0);
            }
            const float4 b4 = *(const float4*)&bias[k0 + kt * 16 + quad * 4];
            const float bb4[4] = {b4.x, b4.y, b4.z, b4.w};
#pragma unroll
            for (int r = 0; r < 4; ++r) { sv0[kt][r] = a0[r] * SC2_ + bb4[r];
                                          sv1[kt][r] = a1[r] * SC2_ + bb4[r]; }
        }
        __builtin_amdgcn_s_setprio(0);

        // ---- stage next chunk into other buffers; issue loads for chunk+2.
        // Writes target the buffer whose reads finished before the PREVIOUS
        // barrier, so they legally overlap this chunk's compute.
        if (ch < 15) {
            if (ch & 1) { STAGE_WRITES(kt0, vt0) } else { STAGE_WRITES(kt1, vt1) }
            if (ch < 14) ISSUE_LOADS(ch + 2)
        }

        // ---- online softmax (deferred rescale, T13)
        float ml0 = sv0[0][0], ml1 = sv1[0][0];
#pragma unroll
        for (int kt = 0; kt < 4; ++kt)
#pragma unroll
            for (int r = 0; r < 4; ++r) { ml0 = fmaxf(ml0, sv0[kt][r]); ml1 = fmaxf(ml1, sv1[kt][r]); }
        ml0 = fmaxf(ml0, __shfl_xor(ml0, 16, 64)); ml0 = fmaxf(ml0, __shfl_xor(ml0, 32, 64));
        ml1 = fmaxf(ml1, __shfl_xor(ml1, 16, 64)); ml1 = fmaxf(ml1, __shfl_xor(ml1, 32, 64));

        if (__any((ml0 > mrun0 + DTHR_) || (ml1 > mrun1 + DTHR_))) {
            const float mn0 = fmaxf(mrun0, ml0), mn1 = fmaxf(mrun1, ml1);
            const float al0 = exp2f(mrun0 - mn0), al1 = exp2f(mrun1 - mn1);
            lrun0 *= al0; lrun1 *= al1;
            mrun0 = mn0;  mrun1 = mn1;
            float ar0[4], ar1[4];
#pragma unroll
            for (int r = 0; r < 4; ++r) { ar0[r] = __shfl(al0, quad * 4 + r, 64);
                                          ar1[r] = __shfl(al1, quad * 4 + r, 64); }
#pragma unroll
            for (int ct = 0; ct < 8; ++ct)
#pragma unroll
                for (int r = 0; r < 4; ++r) { ac0[ct][r] *= ar0[r]; ac1[ct][r] *= ar1[r]; }
        }

        b4v pk0[4], pk1[4];
        float rs0 = 0.f, rs1 = 0.f;
#pragma unroll
        for (int kt = 0; kt < 4; ++kt)
#pragma unroll
            for (int r = 0; r < 4; ++r) {
                const float p0 = exp2f(sv0[kt][r] - mrun0); rs0 += p0; pk0[kt][r] = (__bf16)p0;
                const float p1 = exp2f(sv1[kt][r] - mrun1); rs1 += p1; pk1[kt][r] = (__bf16)p1;
            }
        rs0 += __shfl_xor(rs0, 16, 64); rs0 += __shfl_xor(rs0, 32, 64);
        rs1 += __shfl_xor(rs1, 16, 64); rs1 += __shfl_xor(rs1, 32, 64);
        lrun0 += rs0; lrun1 += rs1;

        // ---- GEMM2: interleaved V rows -> single b128 per fragment
        const b8v A00 = __builtin_shufflevector(pk0[0], pk0[1], 0, 1, 2, 3, 4, 5, 6, 7);
        const b8v A01 = __builtin_shufflevector(pk0[2], pk0[3], 0, 1, 2, 3, 4, 5, 6, 7);
        const b8v A10 = __builtin_shufflevector(pk1[0], pk1[1], 0, 1, 2, 3, 4, 5, 6, 7);
        const b8v A11 = __builtin_shufflevector(pk1[2], pk1[3], 0, 1, 2, 3, 4, 5, 6, 7);
        __builtin_amdgcn_s_setprio(1);
#pragma unroll
        for (int ct = 0; ct < 8; ++ct) {
            const char* vrow = vtc + (ct * 16 + pl) * VSTRIDE + quad * 16;
            const b8v B0 = ldb8(vrow);
            const b8v B1 = ldb8(vrow + 64);
            ac0[ct] = __builtin_amdgcn_mfma_f32_16x16x32_bf16(A00, B0, ac0[ct], 0, 0, 0);
            ac0[ct] = __builtin_amdgcn_mfma_f32_16x16x32_bf16(A01, B1, ac0[ct], 0, 0, 0);
            ac1[ct] = __builtin_amdgcn_mfma_f32_16x16x32_bf16(A10, B0, ac1[ct], 0, 0, 0);
            ac1[ct] = __builtin_amdgcn_mfma_f32_16x16x32_bf16(A11, B1, ac1[ct], 0, 0, 0);
        }
        __builtin_amdgcn_s_setprio(0);

        RAW_BARRIER()                          // global prefetch stays in flight
    }
#undef ISSUE_LOADS
#undef STAGE_WRITES
#undef RAW_BARRIER

    // ---- epilogue: normalized ctx -> RA [pos][c] bf16
    {
        float inv0[4], inv1[4];
#pragma unroll
        for (int r = 0; r < 4; ++r) { inv0[r] = 1.f / __shfl(lrun0, quad * 4 + r, 64);
                                      inv1[r] = 1.f / __shfl(lrun1, quad * 4 + r, 64); }
#pragma unroll
        for (int ct = 0; ct < 8; ++ct)
#pragma unroll
            for (int r = 0; r < 4; ++r) {
                RAh[(w * 32 + quad * 4 + r) * 136 + ct * 16 + pl]      = (__bf16)(ac0[ct][r] * inv0[r]);
                RAh[(w * 32 + 16 + quad * 4 + r) * 136 + ct * 16 + pl] = (__bf16)(ac1[ct][r] * inv1[r]);
            }
    }
    __syncthreads();                           // sync5: ctx in RA

    // ================= phase 3: final =================
    b8v Wof[2][4];
#pragma unroll
    for (int mt = 0; mt < 2; ++mt)
#pragma unroll
        for (int s = 0; s < 4; ++s)
            Wof[mt][s] = ldb8(Wop + (ob + mt * 16 + pl) * 128 + s * 32 + quad * 8);

    const char* qg2 = (const char*)(qt + ((size_t)b * HW_ + n0) * 128) + t * 16;
    float4 q_s0 = *(const float4*)(qg2);
    float4 q_s1 = *(const float4*)(qg2 + 4096);
    float4 q_s2 = *(const float4*)(qg2 + 8192);
    float4 q_s3 = *(const float4*)(qg2 + 12288);
    float4 q_s4 = *(const float4*)(qg2 + 16384);
    float4 q_s5 = *(const float4*)(qg2 + 20480);
    float4 q_s6 = *(const float4*)(qg2 + 24576);
    float4 q_s7 = *(const float4*)(qg2 + 28672);

    {
        f4v f1[2][8];
#pragma unroll
        for (int mt = 0; mt < 2; ++mt)
#pragma unroll
            for (int nt = 0; nt < 8; ++nt) f1[mt][nt] = (f4v){0.f, 0.f, 0.f, 0.f};
#pragma unroll
        for (int s = 0; s < 4; ++s) {
            b8v Bf[8];
#pragma unroll
            for (int nt = 0; nt < 8; ++nt)
                Bf[nt] = ldb8(RA + (nt * 16 + pl) * XSTRIDE + s * 64 + quad * 16);
#pragma unroll
            for (int mt = 0; mt < 2; ++mt)
#pragma unroll
                for (int nt = 0; nt < 8; ++nt)
                    f1[mt][nt] = __builtin_amdgcn_mfma_f32_16x16x32_bf16(Wof[mt][s], Bf[nt], f1[mt][nt], 0, 0, 0);
        }
#pragma unroll
        for (int mt = 0; mt < 2; ++mt) {
            const float4 s4 = *(const float4*)(bo + ob + mt * 16 + quad * 4);
            const float shf[4] = {s4.x, s4.y, s4.z, s4.w};
#pragma unroll
            for (int nt = 0; nt < 8; ++nt) {
                b4v y;
#pragma unroll
                for (int r = 0; r < 4; ++r) y[r] = (__bf16)fmaxf(f1[mt][nt][r] + shf[r], 0.f);
                *(b4v*)&RBh[(nt * 16 + pl) * 136 + ob + mt * 16 + quad * 4] = y;
            }
        }
    }
    __syncthreads();                           // sync6: ctx2 in RB, RA reads done

    *(float4*)(xl)                 = q_s0;
    *(float4*)(xl + 16 * XSTRIDE)  = q_s1;
    *(float4*)(xl + 32 * XSTRIDE)  = q_s2;
    *(float4*)(xl + 48 * XSTRIDE)  = q_s3;
    *(float4*)(xl + 64 * XSTRIDE)  = q_s4;
    *(float4*)(xl + 80 * XSTRIDE)  = q_s5;
    *(float4*)(xl + 96 * XSTRIDE)  = q_s6;
    *(float4*)(xl + 112 * XSTRIDE) = q_s7;
    __syncthreads();                           // sync7: qt in RA

    {
        f4v f2[4][8];
#pragma unroll
        for (int mt = 0; mt < 4; ++mt)
#pragma unroll
            for (int nt = 0; nt < 8; ++nt) f2[mt][nt] = (f4v){0.f, 0.f, 0.f, 0.f};
#pragma unroll
        for (int ks = 0; ks < 8; ++ks) {
            b8v Af[4];
#pragma unroll
            for (int mt = 0; mt < 4; ++mt)
                Af[mt] = ldb8(Wbp + (size_t)(64 * w + mt * 16 + pl) * 256 + ks * 32 + quad * 8);
            b8v Bf[8];
            if (ks < 4) {
#pragma unroll
                for (int nt = 0; nt < 8; ++nt)
                    Bf[nt] = *(const b8v*)&RBh[(nt * 16 + pl) * 136 + ks * 32 + quad * 8];
            } else {
#pragma unroll
                for (int nt = 0; nt < 8; ++nt)
                    Bf[nt] = ldb8(RA + (nt * 16 + pl) * XSTRIDE + (ks - 4) * 64 + quad * 16);
            }
#pragma unroll
            for (int mt = 0; mt < 4; ++mt)
#pragma unroll
                for (int nt = 0; nt < 8; ++nt)
                    f2[mt][nt] = __builtin_amdgcn_mfma_f32_16x16x32_bf16(Af[mt], Bf[nt], f2[mt][nt], 0, 0, 0);
        }
#pragma unroll
        for (int mt = 0; mt < 4; ++mt) {
            const float4 s4 = *(const float4*)(bb + 64 * w + mt * 16 + quad * 4);
            const float shf[4] = {s4.x, s4.y, s4.z, s4.w};
#pragma unroll
            for (int nt = 0; nt < 8; ++nt)
#pragma unroll
                for (int r = 0; r < 4; ++r)
                    out[(size_t)(b * 256 + 64 * w + mt * 16 + quad * 4 + r) * HW_ + n0 + nt * 16 + pl]
                        = fmaxf(f2[mt][nt][r] + shf[r], 0.f);
        }
    }
}

// ---------------------------------------------------------------------------
extern "C" void kernel_launch(void* const* d_in, const int* in_sizes, int n_in,
                              void* d_out, int out_size, void* d_ws, size_t ws_size,
                              hipStream_t stream)
{
    const float* query = (const float*)d_in[0];
    const float* key   = (const float*)d_in[1];
    const float* val   = (const float*)d_in[2];
    const int*   mask  = (const int*)  d_in[3];
    const float* Wq1 = (const float*)d_in[4];  const float* sq1 = (const float*)d_in[5];  const float* bq1 = (const float*)d_in[6];
    const float* Wq2 = (const float*)d_in[7];  const float* sq2 = (const float*)d_in[8];  const float* bq2 = (const float*)d_in[9];
    const float* Wk1 = (const float*)d_in[10]; const float* sk1 = (const float*)d_in[11]; const float* bk1 = (const float*)d_in[12];
    const float* Wk2 = (const float*)d_in[13]; const float* sk2 = (const float*)d_in[14]; const float* bk2 = (const float*)d_in[15];
    const float* Wv  = (const float*)d_in[16]; const float* sv  = (const float*)d_in[17]; const float* bv  = (const float*)d_in[18];
    const float* Wo  = (const float*)d_in[19]; const float* so  = (const float*)d_in[20]; const float* bo  = (const float*)d_in[21];
    const float* Wb  = (const float*)d_in[22]; const float* sb  = (const float*)d_in[23]; const float* bb  = (const float*)d_in[24];

    char* ws = (char*)d_ws;
    bf16*   qt   = (bf16*)(ws);                        // [B][HW][C] bf16 : 16 MB
    bf16*   kbuf = (bf16*)(ws + (16u << 20));          // [B][K][C]  bf16 : 1 MB
    bf16*   vbuf = (bf16*)(ws + (17u << 20));          // [B][C][K]  bf16 : 1 MB
    char*   wbase = ws + (18u << 20);
    __bf16* Wq1p = (__bf16*)(wbase);
    __bf16* Wq2p = (__bf16*)(wbase + (32u << 10));
    __bf16* Wop  = (__bf16*)(wbase + (64u << 10));
    __bf16* Wbp  = (__bf16*)(wbase + (96u << 10));     // 128 KB
    float* outp = (float*)d_out;

    prep_kernel<<<1504, 256, 0, stream>>>(
        query, key, val,
        Wq1, sq1, Wq2, sq2, Wo, so, Wb, sb,
        Wk1, sk1, bk1, Wk2, sk2, bk2, Wv, sv, bv,
        qt, kbuf, vbuf, Wq1p, Wq2p, Wop, Wbp);
    mega_kernel<<<dim3(HW_ / 128, B_), 256, 0, stream>>>(
        qt, kbuf, vbuf, mask,
        Wq1p, bq1, Wq2p, bq2, Wop, bo, Wbp, bb, outp);
}

// Round 2
// 231.275 us; speedup vs baseline: 1.0018x; 1.0018x over previous
//
#include <hip/hip_runtime.h>
#include <hip/hip_bf16.h>

#define B_    4
#define C_    128
#define HW_   16384
#define K_    1024
// softmax runs in log2 domain: fold 128^-0.5 * log2(e) into the QK epilogue FMA
#define SC2_  0.12751734f
#define NEGL_ (-1.4427e7f)        // NEG * log2(e)
#define DTHR_ 8.0f                // defer-max threshold (log2 units): p <= 2^8

using bf16 = __hip_bfloat16;
typedef __bf16 b8v __attribute__((ext_vector_type(8)));
typedef __bf16 b4v __attribute__((ext_vector_type(4)));
typedef __bf16 b2v __attribute__((ext_vector_type(2)));
typedef float  f4v __attribute__((ext_vector_type(4)));

__device__ __forceinline__ b8v ldb8(const void* p) { return *(const b8v*)p; }
__device__ __forceinline__ b4v ldb4(const void* p) { return *(const b4v*)p; }

#define XSTRIDE 272   // 256 B row + 16 pad (b128 frag reads at bank floor)
#define KSTRIDE 272
#define VSTRIDE 136   // R0-proven V layout: 128 B row + 8 pad, ldb4-pair reads

// weight row (f32) -> bf16 fragment with BN scale folded, inline
__device__ __forceinline__ b8v ldw8(const float* wp, float sc) {
    const float4 a = *(const float4*)wp;
    const float4 c = *(const float4*)(wp + 4);
    b8v r;
    r[0] = (__bf16)(a.x * sc); r[1] = (__bf16)(a.y * sc);
    r[2] = (__bf16)(a.z * sc); r[3] = (__bf16)(a.w * sc);
    r[4] = (__bf16)(c.x * sc); r[5] = (__bf16)(c.y * sc);
    r[6] = (__bf16)(c.z * sc); r[7] = (__bf16)(c.w * sc);
    return r;
}

// ---------------------------------------------------------------------------
// prep: merged prep1 + kvproj (kept from R1, ~neutral but one fewer launch).
//   blk [0,32)       : self-contained k/v projection blocks -> kbuf, vbuf
//   blk [32,1056)    : query transpose  f32 [b][c][p] -> bf16 qt [b][p][c]
//   blk [1056,1504)  : mega weight prep (Wq1,Wq2,Wo,Wb)
// ---------------------------------------------------------------------------
__global__ __launch_bounds__(256, 2) void prep_kernel(
    const float* __restrict__ query, const float* __restrict__ key, const float* __restrict__ val,
    const float* __restrict__ Wq1, const float* __restrict__ sq1,
    const float* __restrict__ Wq2, const float* __restrict__ sq2,
    const float* __restrict__ Wo,  const float* __restrict__ so,
    const float* __restrict__ Wb,  const float* __restrict__ sb,
    const float* __restrict__ Wk1, const float* __restrict__ sk1, const float* __restrict__ bk1,
    const float* __restrict__ Wk2, const float* __restrict__ sk2, const float* __restrict__ bk2,
    const float* __restrict__ Wv,  const float* __restrict__ sv_, const float* __restrict__ bv,
    bf16* __restrict__ qt, bf16* __restrict__ kbuf, bf16* __restrict__ vbuf,
    __bf16* __restrict__ Wq1p, __bf16* __restrict__ Wq2p,
    __bf16* __restrict__ Wop,  __bf16* __restrict__ Wbp)
{
    __shared__ __align__(16) char SM[69632];
    const int blk = blockIdx.x, t = threadIdx.x;

    if (blk < 32) {
        // ================= fused k/v projection =================
        const int b = blk >> 3, n0 = (blk & 7) * 128;
        const int w = t >> 6, lane = t & 63;
        const int pl = lane & 15, quad = lane >> 4;
        const int ob = 32 * w;
        const int plT = t & 63, cg = t >> 6;
        char*    Xs  = SM;                       // bf16 [128 pos][XSTRIDE]
        __bf16*  Ys  = (__bf16*)(SM + 34816);    // bf16 [128][136]
        float*   Tmp = (float*)(SM + 34816);     // f32 [64][129] (aliases Ys)

        auto transpose_in = [&](const float* src) {
#pragma unroll
            for (int h = 0; h < 2; ++h) {
                const int p0 = n0 + h * 64;
#pragma unroll 4
                for (int i2 = 0; i2 < 32; ++i2) {
                    const int c = cg * 32 + i2;
                    Tmp[plT * 129 + c] = src[(size_t)(b * 128 + c) * K_ + p0 + plT];
                }
                __syncthreads();
#pragma unroll 4
                for (int it = 0; it < 16; ++it) {
                    const int p = it * 4 + cg;
                    b2v pk2;
                    pk2[0] = (__bf16)Tmp[p * 129 + 2 * plT];
                    pk2[1] = (__bf16)Tmp[p * 129 + 2 * plT + 1];
                    *(b2v*)(Xs + (h * 64 + p) * XSTRIDE + 4 * plT) = pk2;
                }
                __syncthreads();
            }
        };

        // ---- K projection (2 layers) ----
        transpose_in(key);
        b8v W1f[2][4], W2f[2][4];
#pragma unroll
        for (int mt = 0; mt < 2; ++mt)
#pragma unroll
            for (int s = 0; s < 4; ++s) {
                const int row = ob + mt * 16 + pl;
                W1f[mt][s] = ldw8(Wk1 + row * 128 + s * 32 + quad * 8, sk1[row]);
                W2f[mt][s] = ldw8(Wk2 + row * 128 + s * 32 + quad * 8, sk2[row]);
            }
        {
            f4v acc[2][8];
#pragma unroll
            for (int mt = 0; mt < 2; ++mt)
#pragma unroll
                for (int nt = 0; nt < 8; ++nt) acc[mt][nt] = (f4v){0.f, 0.f, 0.f, 0.f};
#pragma unroll
            for (int s = 0; s < 4; ++s) {
                b8v Bf[8];
#pragma unroll
                for (int nt = 0; nt < 8; ++nt)
                    Bf[nt] = ldb8(Xs + (nt * 16 + pl) * XSTRIDE + s * 64 + quad * 16);
#pragma unroll
                for (int mt = 0; mt < 2; ++mt)
#pragma unroll
                    for (int nt = 0; nt < 8; ++nt)
                        acc[mt][nt] = __builtin_amdgcn_mfma_f32_16x16x32_bf16(W1f[mt][s], Bf[nt], acc[mt][nt], 0, 0, 0);
            }
#pragma unroll
            for (int mt = 0; mt < 2; ++mt) {
                const float4 s4 = *(const float4*)(bk1 + ob + mt * 16 + quad * 4);
                const float shf[4] = {s4.x, s4.y, s4.z, s4.w};
#pragma unroll
                for (int nt = 0; nt < 8; ++nt) {
                    b4v y;
#pragma unroll
                    for (int r = 0; r < 4; ++r) y[r] = (__bf16)fmaxf(acc[mt][nt][r] + shf[r], 0.f);
                    *(b4v*)&Ys[(nt * 16 + pl) * 136 + ob + mt * 16 + quad * 4] = y;
                }
            }
        }
        __syncthreads();
        {
            f4v acc2[2][8];
#pragma unroll
            for (int mt = 0; mt < 2; ++mt)
#pragma unroll
                for (int nt = 0; nt < 8; ++nt) acc2[mt][nt] = (f4v){0.f, 0.f, 0.f, 0.f};
#pragma unroll
            for (int s = 0; s < 4; ++s) {
                b8v Bf[8];
#pragma unroll
                for (int nt = 0; nt < 8; ++nt)
                    Bf[nt] = *(const b8v*)&Ys[(nt * 16 + pl) * 136 + s * 32 + quad * 8];
#pragma unroll
                for (int mt = 0; mt < 2; ++mt)
#pragma unroll
                    for (int nt = 0; nt < 8; ++nt)
                        acc2[mt][nt] = __builtin_amdgcn_mfma_f32_16x16x32_bf16(W2f[mt][s], Bf[nt], acc2[mt][nt], 0, 0, 0);
            }
            bf16* kdst = kbuf + ((size_t)b * K_ + n0) * 128;
#pragma unroll
            for (int mt = 0; mt < 2; ++mt) {
                const float4 s4 = *(const float4*)(bk2 + ob + mt * 16 + quad * 4);
                const float shf[4] = {s4.x, s4.y, s4.z, s4.w};
#pragma unroll
                for (int nt = 0; nt < 8; ++nt) {
                    b4v y;
#pragma unroll
                    for (int r = 0; r < 4; ++r) y[r] = (__bf16)fmaxf(acc2[mt][nt][r] + shf[r], 0.f);
                    *(b4v*)(kdst + (size_t)(nt * 16 + pl) * 128 + ob + mt * 16 + quad * 4) = y;
                }
            }
        }
        __syncthreads();   // Ys reads done before val-transpose reuses Tmp

        // ---- V projection (1 layer) ----
        transpose_in(val);
        b8v Wvf[2][4];
#pragma unroll
        for (int mt = 0; mt < 2; ++mt)
#pragma unroll
            for (int s = 0; s < 4; ++s) {
                const int row = ob + mt * 16 + pl;
                Wvf[mt][s] = ldw8(Wv + row * 128 + s * 32 + quad * 8, sv_[row]);
            }
        {
            f4v acc[2][8];
#pragma unroll
            for (int mt = 0; mt < 2; ++mt)
#pragma unroll
                for (int nt = 0; nt < 8; ++nt) acc[mt][nt] = (f4v){0.f, 0.f, 0.f, 0.f};
#pragma unroll
            for (int s = 0; s < 4; ++s) {
                b8v Bf[8];
#pragma unroll
                for (int nt = 0; nt < 8; ++nt)
                    Bf[nt] = ldb8(Xs + (nt * 16 + pl) * XSTRIDE + s * 64 + quad * 16);
#pragma unroll
                for (int mt = 0; mt < 2; ++mt)
#pragma unroll
                    for (int nt = 0; nt < 8; ++nt)
                        acc[mt][nt] = __builtin_amdgcn_mfma_f32_16x16x32_bf16(Wvf[mt][s], Bf[nt], acc[mt][nt], 0, 0, 0);
            }
            bf16* vdst = vbuf + (size_t)b * 128 * K_;
#pragma unroll
            for (int mt = 0; mt < 2; ++mt) {
                const float4 s4 = *(const float4*)(bv + ob + mt * 16 + quad * 4);
                const float shf[4] = {s4.x, s4.y, s4.z, s4.w};
#pragma unroll
                for (int nt = 0; nt < 8; ++nt)
#pragma unroll
                    for (int r = 0; r < 4; ++r)
                        vdst[(size_t)(ob + mt * 16 + quad * 4 + r) * K_ + n0 + nt * 16 + pl]
                            = __float2bfloat16(fmaxf(acc[mt][nt][r] + shf[r], 0.f));
            }
        }
    } else if (blk < 1056) {
        // ================= query transpose =================
        float* Xs2 = (float*)SM;
        const int i = blk - 32;
        const int b = i >> 8, p0 = (i & 255) * 64;
        const int pl = t & 63, cg = t >> 6;
#pragma unroll 4
        for (int i2 = 0; i2 < 32; ++i2) {
            const int c = cg * 32 + i2;
            Xs2[pl * 129 + c] = query[(size_t)(b * 128 + c) * HW_ + p0 + pl];
        }
        __syncthreads();
#pragma unroll 4
        for (int it = 0; it < 16; ++it) {
            const int p = it * 4 + cg;
            b2v pk2;
            pk2[0] = (__bf16)Xs2[p * 129 + 2 * pl];
            pk2[1] = (__bf16)Xs2[p * 129 + 2 * pl + 1];
            *(b2v*)(qt + ((size_t)b * HW_ + p0 + p) * 128 + 2 * pl) = pk2;
        }
    } else {
        // ================= mega weight prep =================
        const int idx = (blk - 1056) * 256 + t;
        if (idx < 16384)      { Wq1p[idx] = (__bf16)(Wq1[idx] * sq1[idx >> 7]); }
        else if (idx < 32768) { const int i2 = idx - 16384; Wq2p[i2] = (__bf16)(Wq2[i2] * sq2[i2 >> 7]); }
        else if (idx < 49152) { const int i2 = idx - 32768; Wop[i2]  = (__bf16)(Wo[i2]  * so[i2 >> 7]); }
        else                  { const int i2 = idx - 49152; Wbp[i2]  = (__bf16)(Wb[i2]  * sb[i2 >> 8]); }
    }
}

// ---------------------------------------------------------------------------
// mega: qproj -> flash attention (R0-proven single-buffer lockstep loop;
// lgkm-only barriers keep the global prefetch in flight; log2 softmax with
// deferred rescale; setprio around MFMA clusters) -> out-project + bottleneck.
// One block = 128 queries, 256 threads, grid (HW/128, B). LDS 69632 (2/CU).
// ---------------------------------------------------------------------------
__global__ __launch_bounds__(256, 2) void mega_kernel(
    const bf16* __restrict__ qt, const bf16* __restrict__ kbuf, const bf16* __restrict__ vbuf,
    const int* __restrict__ mask,
    const __bf16* __restrict__ Wq1p, const float* __restrict__ bq1,
    const __bf16* __restrict__ Wq2p, const float* __restrict__ bq2,
    const __bf16* __restrict__ Wop,  const float* __restrict__ bo,
    const __bf16* __restrict__ Wbp,  const float* __restrict__ bb,
    float* __restrict__ out)
{
    __shared__ __align__(16) char S[69632];

    const int t = threadIdx.x, w = t >> 6, lane = t & 63;
    const int pl = lane & 15, quad = lane >> 4;
    const int n0 = blockIdx.x * 128;
    const int b  = blockIdx.y;
    const int ob = 32 * w;

    char*   RA  = S;
    __bf16* RAh = (__bf16*)S;
    __bf16* RBh = (__bf16*)(S + 34816);
    char* xl = RA + (t >> 4) * XSTRIDE + (t & 15) * 16;

    // ================= phase 1: q projection (into LDS) =================
    {
        const char* qg = (const char*)(qt + ((size_t)b * HW_ + n0) * 128) + t * 16;
#pragma unroll
        for (int i = 0; i < 8; ++i)
            *(float4*)(xl + i * 16 * XSTRIDE) = *(const float4*)(qg + i * 4096);
    }
    {
        b8v W1f[2][4], W2f[2][4];
#pragma unroll
        for (int mt = 0; mt < 2; ++mt)
#pragma unroll
            for (int s = 0; s < 4; ++s) {
                W1f[mt][s] = ldb8(Wq1p + (ob + mt * 16 + pl) * 128 + s * 32 + quad * 8);
                W2f[mt][s] = ldb8(Wq2p + (ob + mt * 16 + pl) * 128 + s * 32 + quad * 8);
            }
        __syncthreads();                       // sync1: q-tile in RA

        f4v a1[2][8];
#pragma unroll
        for (int mt = 0; mt < 2; ++mt)
#pragma unroll
            for (int nt = 0; nt < 8; ++nt) a1[mt][nt] = (f4v){0.f, 0.f, 0.f, 0.f};
#pragma unroll
        for (int s = 0; s < 4; ++s) {
            b8v Bf[8];
#pragma unroll
            for (int nt = 0; nt < 8; ++nt)
                Bf[nt] = ldb8(RA + (nt * 16 + pl) * XSTRIDE + s * 64 + quad * 16);
#pragma unroll
            for (int mt = 0; mt < 2; ++mt)
#pragma unroll
                for (int nt = 0; nt < 8; ++nt)
                    a1[mt][nt] = __builtin_amdgcn_mfma_f32_16x16x32_bf16(W1f[mt][s], Bf[nt], a1[mt][nt], 0, 0, 0);
        }
#pragma unroll
        for (int mt = 0; mt < 2; ++mt) {
            const float4 s4 = *(const float4*)(bq1 + ob + mt * 16 + quad * 4);
            const float shf[4] = {s4.x, s4.y, s4.z, s4.w};
#pragma unroll
            for (int nt = 0; nt < 8; ++nt) {
                b4v y;
#pragma unroll
                for (int r = 0; r < 4; ++r) y[r] = (__bf16)fmaxf(a1[mt][nt][r] + shf[r], 0.f);
                *(b4v*)&RBh[(nt * 16 + pl) * 136 + ob + mt * 16 + quad * 4] = y;
            }
        }
        __syncthreads();                       // sync2: y1 in RB, RA reads done

        f4v a2[2][8];
#pragma unroll
        for (int mt = 0; mt < 2; ++mt)
#pragma unroll
            for (int nt = 0; nt < 8; ++nt) a2[mt][nt] = (f4v){0.f, 0.f, 0.f, 0.f};
#pragma unroll
        for (int s = 0; s < 4; ++s) {
            b8v Bf[8];
#pragma unroll
            for (int nt = 0; nt < 8; ++nt)
                Bf[nt] = *(const b8v*)&RBh[(nt * 16 + pl) * 136 + s * 32 + quad * 8];
#pragma unroll
            for (int mt = 0; mt < 2; ++mt)
#pragma unroll
                for (int nt = 0; nt < 8; ++nt)
                    a2[mt][nt] = __builtin_amdgcn_mfma_f32_16x16x32_bf16(W2f[mt][s], Bf[nt], a2[mt][nt], 0, 0, 0);
        }
#pragma unroll
        for (int mt = 0; mt < 2; ++mt) {
            const float4 s4 = *(const float4*)(bq2 + ob + mt * 16 + quad * 4);
            const float shf[4] = {s4.x, s4.y, s4.z, s4.w};
#pragma unroll
            for (int nt = 0; nt < 8; ++nt) {
                b4v y;
#pragma unroll
                for (int r = 0; r < 4; ++r) y[r] = (__bf16)fmaxf(a2[mt][nt][r] + shf[r], 0.f);
                *(b4v*)&RAh[(nt * 16 + pl) * 136 + ob + mt * 16 + quad * 4] = y;
            }
        }
        __syncthreads();                       // sync3: q[pos][c] in RA
    }

    // q fragments: wave w owns queries w*32..w*32+31 (2 tiles)
    b8v qf0[4], qf1[4];
#pragma unroll
    for (int s = 0; s < 4; ++s) {
        qf0[s] = ldb8(RA + (w * 32 + pl) * XSTRIDE + s * 64 + quad * 16);
        qf1[s] = ldb8(RA + (w * 32 + 16 + pl) * XSTRIDE + s * 64 + quad * 16);
    }
    __syncthreads();                           // sync4: qf read, RA free

    // ================= phase 2: attention =================
    float* bias = (float*)S;                   // 4096 B
    char* ktile = S + 4096;                    // 64*272 = 17408 B
    char* vtile = S + 34816;                   // 128*136 = 17408 B

    for (int i2 = t; i2 < K_; i2 += 256)
        bias[i2] = (mask[b * K_ + i2] != 0) ? 0.f : NEGL_;

    const bf16* kpt = kbuf + (size_t)b * K_ * 128;
    const bf16* vpt = vbuf + (size_t)b * 128 * K_;
    const char* kg = (const char*)kpt + t * 16;
    const char* vg = (const char*)(vpt + (size_t)(t >> 3) * K_) + (t & 7) * 16;
    char* kl = ktile + (t >> 4) * KSTRIDE + (t & 15) * 16;
    char* vl = vtile + (t >> 3) * VSTRIDE + (t & 7) * 16;

    float4 k_r0 = *(const float4*)(kg);
    float4 k_r1 = *(const float4*)(kg + 4096);
    float4 k_r2 = *(const float4*)(kg + 8192);
    float4 k_r3 = *(const float4*)(kg + 12288);
    float4 v_r0 = *(const float4*)(vg);
    float4 v_r1 = *(const float4*)(vg + 65536);
    float4 v_r2 = *(const float4*)(vg + 131072);
    float4 v_r3 = *(const float4*)(vg + 196608);

    f4v ac0[8], ac1[8];
#pragma unroll
    for (int i = 0; i < 8; ++i) { ac0[i] = (f4v){0.f,0.f,0.f,0.f}; ac1[i] = (f4v){0.f,0.f,0.f,0.f}; }
    float mrun0 = -3.0e38f, mrun1 = -3.0e38f, lrun0 = 0.f, lrun1 = 0.f;

    // lgkm-only barrier: LDS ops drained, global prefetch stays in flight.
    // sched_barrier(0) fences prevent hoisting past the wait (rule #18).
#define RAW_BARRIER()                                                 \
    __builtin_amdgcn_sched_barrier(0);                                \
    asm volatile("s_waitcnt lgkmcnt(0)" ::: "memory");                \
    __builtin_amdgcn_s_barrier();                                     \
    __builtin_amdgcn_sched_barrier(0);

    for (int chunk = 0; chunk < 16; ++chunk) {
        const int k0 = chunk * 64;

        *(float4*)(kl)                = k_r0;
        *(float4*)(kl + 16 * KSTRIDE) = k_r1;
        *(float4*)(kl + 32 * KSTRIDE) = k_r2;
        *(float4*)(kl + 48 * KSTRIDE) = k_r3;
        *(float4*)(vl)                = v_r0;
        *(float4*)(vl + 32 * VSTRIDE) = v_r1;
        *(float4*)(vl + 64 * VSTRIDE) = v_r2;
        *(float4*)(vl + 96 * VSTRIDE) = v_r3;
        RAW_BARRIER()                          // tile visible; no vmcnt drain

        if (chunk < 15) {
            const char* kgn = kg + (chunk + 1) * 16384;
            const char* vgn = vg + (chunk + 1) * 128;
            k_r0 = *(const float4*)(kgn);
            k_r1 = *(const float4*)(kgn + 4096);
            k_r2 = *(const float4*)(kgn + 8192);
            k_r3 = *(const float4*)(kgn + 12288);
            v_r0 = *(const float4*)(vgn);
            v_r1 = *(const float4*)(vgn + 65536);
            v_r2 = *(const float4*)(vgn + 131072);
            v_r3 = *(const float4*)(vgn + 196608);
        }

        // ---- GEMM1: k-frags loaded once, used for both q-tiles (log2 scores)
        f4v sv0[4], sv1[4];
        __builtin_amdgcn_s_setprio(1);
#pragma unroll
        for (int kt = 0; kt < 4; ++kt) {
            f4v a0 = (f4v){0.f,0.f,0.f,0.f}, a1 = (f4v){0.f,0.f,0.f,0.f};
            const char* krow = ktile + (kt * 16 + pl) * KSTRIDE + quad * 16;
#pragma unroll
            for (int s = 0; s < 4; ++s) {
                const b8v kf = ldb8(krow + s * 64);
                a0 = __builtin_amdgcn_mfma_f32_16x16x32_bf16(kf, qf0[s], a0, 0, 0, 0);
                a1 = __builtin_amdgcn_mfma_f32_16x16x32_bf16(kf, qf1[s], a1, 0, 0, 0);
            }
            const float4 b4 = *(const float4*)&bias[k0 + kt * 16 + quad * 4];
            const float bb4[4] = {b4.x, b4.y, b4.z, b4.w};
#pragma unroll
            for (int r = 0; r < 4; ++r) { sv0[kt][r] = a0[r] * SC2_ + bb4[r];
                                          sv1[kt][r] = a1[r] * SC2_ + bb4[r]; }
        }
        __builtin_amdgcn_s_setprio(0);

        // ---- online softmax (deferred rescale, T13)
        float ml0 = sv0[0][0], ml1 = sv1[0][0];
#pragma unroll
        for (int kt = 0; kt < 4; ++kt)
#pragma unroll
            for (int r = 0; r < 4; ++r) { ml0 = fmaxf(ml0, sv0[kt][r]); ml1 = fmaxf(ml1, sv1[kt][r]); }
        ml0 = fmaxf(ml0, __shfl_xor(ml0, 16, 64)); ml0 = fmaxf(ml0, __shfl_xor(ml0, 32, 64));
        ml1 = fmaxf(ml1, __shfl_xor(ml1, 16, 64)); ml1 = fmaxf(ml1, __shfl_xor(ml1, 32, 64));

        if (__any((ml0 > mrun0 + DTHR_) || (ml1 > mrun1 + DTHR_))) {
            const float mn0 = fmaxf(mrun0, ml0), mn1 = fmaxf(mrun1, ml1);
            const float al0 = exp2f(mrun0 - mn0), al1 = exp2f(mrun1 - mn1);
            lrun0 *= al0; lrun1 *= al1;
            mrun0 = mn0;  mrun1 = mn1;
            float ar0[4], ar1[4];
#pragma unroll
            for (int r = 0; r < 4; ++r) { ar0[r] = __shfl(al0, quad * 4 + r, 64);
                                          ar1[r] = __shfl(al1, quad * 4 + r, 64); }
#pragma unroll
            for (int ct = 0; ct < 8; ++ct)
#pragma unroll
                for (int r = 0; r < 4; ++r) { ac0[ct][r] *= ar0[r]; ac1[ct][r] *= ar1[r]; }
        }

        b4v pk0[4], pk1[4];
        float rs0 = 0.f, rs1 = 0.f;
#pragma unroll
        for (int kt = 0; kt < 4; ++kt)
#pragma unroll
            for (int r = 0; r < 4; ++r) {
                const float p0 = exp2f(sv0[kt][r] - mrun0); rs0 += p0; pk0[kt][r] = (__bf16)p0;
                const float p1 = exp2f(sv1[kt][r] - mrun1); rs1 += p1; pk1[kt][r] = (__bf16)p1;
            }
        rs0 += __shfl_xor(rs0, 16, 64); rs0 += __shfl_xor(rs0, 32, 64);
        rs1 += __shfl_xor(rs1, 16, 64); rs1 += __shfl_xor(rs1, 32, 64);
        lrun0 += rs0; lrun1 += rs1;

        // ---- GEMM2: v-frags loaded once, used for both q-tiles (R0 layout)
        const b8v A00 = __builtin_shufflevector(pk0[0], pk0[1], 0, 1, 2, 3, 4, 5, 6, 7);
        const b8v A01 = __builtin_shufflevector(pk0[2], pk0[3], 0, 1, 2, 3, 4, 5, 6, 7);
        const b8v A10 = __builtin_shufflevector(pk1[0], pk1[1], 0, 1, 2, 3, 4, 5, 6, 7);
        const b8v A11 = __builtin_shufflevector(pk1[2], pk1[3], 0, 1, 2, 3, 4, 5, 6, 7);
        __builtin_amdgcn_s_setprio(1);
#pragma unroll
        for (int ct = 0; ct < 8; ++ct) {
            const char* vrow = vtile + (ct * 16 + pl) * VSTRIDE + quad * 8;
            const b8v B0 = __builtin_shufflevector(ldb4(vrow),      ldb4(vrow + 32), 0, 1, 2, 3, 4, 5, 6, 7);
            const b8v B1 = __builtin_shufflevector(ldb4(vrow + 64), ldb4(vrow + 96), 0, 1, 2, 3, 4, 5, 6, 7);
            ac0[ct] = __builtin_amdgcn_mfma_f32_16x16x32_bf16(A00, B0, ac0[ct], 0, 0, 0);
            ac0[ct] = __builtin_amdgcn_mfma_f32_16x16x32_bf16(A01, B1, ac0[ct], 0, 0, 0);
            ac1[ct] = __builtin_amdgcn_mfma_f32_16x16x32_bf16(A10, B0, ac1[ct], 0, 0, 0);
            ac1[ct] = __builtin_amdgcn_mfma_f32_16x16x32_bf16(A11, B1, ac1[ct], 0, 0, 0);
        }
        __builtin_amdgcn_s_setprio(0);

        RAW_BARRIER()                          // reads drained; next writes safe
    }
#undef RAW_BARRIER

    // ---- epilogue: normalized ctx -> RA [pos][c] bf16
    {
        float inv0[4], inv1[4];
#pragma unroll
        for (int r = 0; r < 4; ++r) { inv0[r] = 1.f / __shfl(lrun0, quad * 4 + r, 64);
                                      inv1[r] = 1.f / __shfl(lrun1, quad * 4 + r, 64); }
#pragma unroll
        for (int ct = 0; ct < 8; ++ct)
#pragma unroll
            for (int r = 0; r < 4; ++r) {
                RAh[(w * 32 + quad * 4 + r) * 136 + ct * 16 + pl]      = (__bf16)(ac0[ct][r] * inv0[r]);
                RAh[(w * 32 + 16 + quad * 4 + r) * 136 + ct * 16 + pl] = (__bf16)(ac1[ct][r] * inv1[r]);
            }
    }
    __syncthreads();                           // sync5: ctx in RA

    // ================= phase 3: final =================
    b8v Wof[2][4];
#pragma unroll
    for (int mt = 0; mt < 2; ++mt)
#pragma unroll
        for (int s = 0; s < 4; ++s)
            Wof[mt][s] = ldb8(Wop + (ob + mt * 16 + pl) * 128 + s * 32 + quad * 8);

    const char* qg2 = (const char*)(qt + ((size_t)b * HW_ + n0) * 128) + t * 16;
    float4 q_s0 = *(const float4*)(qg2);
    float4 q_s1 = *(const float4*)(qg2 + 4096);
    float4 q_s2 = *(const float4*)(qg2 + 8192);
    float4 q_s3 = *(const float4*)(qg2 + 12288);
    float4 q_s4 = *(const float4*)(qg2 + 16384);
    float4 q_s5 = *(const float4*)(qg2 + 20480);
    float4 q_s6 = *(const float4*)(qg2 + 24576);
    float4 q_s7 = *(const float4*)(qg2 + 28672);

    {
        f4v f1[2][8];
#pragma unroll
        for (int mt = 0; mt < 2; ++mt)
#pragma unroll
            for (int nt = 0; nt < 8; ++nt) f1[mt][nt] = (f4v){0.f, 0.f, 0.f, 0.f};
#pragma unroll
        for (int s = 0; s < 4; ++s) {
            b8v Bf[8];
#pragma unroll
            for (int nt = 0; nt < 8; ++nt)
                Bf[nt] = ldb8(RA + (nt * 16 + pl) * XSTRIDE + s * 64 + quad * 16);
#pragma unroll
            for (int mt = 0; mt < 2; ++mt)
#pragma unroll
                for (int nt = 0; nt < 8; ++nt)
                    f1[mt][nt] = __builtin_amdgcn_mfma_f32_16x16x32_bf16(Wof[mt][s], Bf[nt], f1[mt][nt], 0, 0, 0);
        }
#pragma unroll
        for (int mt = 0; mt < 2; ++mt) {
            const float4 s4 = *(const float4*)(bo + ob + mt * 16 + quad * 4);
            const float shf[4] = {s4.x, s4.y, s4.z, s4.w};
#pragma unroll
            for (int nt = 0; nt < 8; ++nt) {
                b4v y;
#pragma unroll
                for (int r = 0; r < 4; ++r) y[r] = (__bf16)fmaxf(f1[mt][nt][r] + shf[r], 0.f);
                *(b4v*)&RBh[(nt * 16 + pl) * 136 + ob + mt * 16 + quad * 4] = y;
            }
        }
    }
    __syncthreads();                           // sync6: ctx2 in RB, RA reads done

    *(float4*)(xl)                 = q_s0;
    *(float4*)(xl + 16 * XSTRIDE)  = q_s1;
    *(float4*)(xl + 32 * XSTRIDE)  = q_s2;
    *(float4*)(xl + 48 * XSTRIDE)  = q_s3;
    *(float4*)(xl + 64 * XSTRIDE)  = q_s4;
    *(float4*)(xl + 80 * XSTRIDE)  = q_s5;
    *(float4*)(xl + 96 * XSTRIDE)  = q_s6;
    *(float4*)(xl + 112 * XSTRIDE) = q_s7;
    __syncthreads();                           // sync7: qt in RA

    {
        f4v f2[4][8];
#pragma unroll
        for (int mt = 0; mt < 4; ++mt)
#pragma unroll
            for (int nt = 0; nt < 8; ++nt) f2[mt][nt] = (f4v){0.f, 0.f, 0.f, 0.f};
#pragma unroll
        for (int ks = 0; ks < 8; ++ks) {
            b8v Af[4];
#pragma unroll
            for (int mt = 0; mt < 4; ++mt)
                Af[mt] = ldb8(Wbp + (size_t)(64 * w + mt * 16 + pl) * 256 + ks * 32 + quad * 8);
            b8v Bf[8];
            if (ks < 4) {
#pragma unroll
                for (int nt = 0; nt < 8; ++nt)
                    Bf[nt] = *(const b8v*)&RBh[(nt * 16 + pl) * 136 + ks * 32 + quad * 8];
            } else {
#pragma unroll
                for (int nt = 0; nt < 8; ++nt)
                    Bf[nt] = ldb8(RA + (nt * 16 + pl) * XSTRIDE + (ks - 4) * 64 + quad * 16);
            }
#pragma unroll
            for (int mt = 0; mt < 4; ++mt)
#pragma unroll
                for (int nt = 0; nt < 8; ++nt)
                    f2[mt][nt] = __builtin_amdgcn_mfma_f32_16x16x32_bf16(Af[mt], Bf[nt], f2[mt][nt], 0, 0, 0);
        }
#pragma unroll
        for (int mt = 0; mt < 4; ++mt) {
            const float4 s4 = *(const float4*)(bb + 64 * w + mt * 16 + quad * 4);
            const float shf[4] = {s4.x, s4.y, s4.z, s4.w};
#pragma unroll
            for (int nt = 0; nt < 8; ++nt)
#pragma unroll
                for (int r = 0; r < 4; ++r)
                    out[(size_t)(b * 256 + 64 * w + mt * 16 + quad * 4 + r) * HW_ + n0 + nt * 16 + pl]
                        = fmaxf(f2[mt][nt][r] + shf[r], 0.f);
        }
    }
}

// ---------------------------------------------------------------------------
extern "C" void kernel_launch(void* const* d_in, const int* in_sizes, int n_in,
                              void* d_out, int out_size, void* d_ws, size_t ws_size,
                              hipStream_t stream)
{
    const float* query = (const float*)d_in[0];
    const float* key   = (const float*)d_in[1];
    const float* val   = (const float*)d_in[2];
    const int*   mask  = (const int*)  d_in[3];
    const float* Wq1 = (const float*)d_in[4];  const float* sq1 = (const float*)d_in[5];  const float* bq1 = (const float*)d_in[6];
    const float* Wq2 = (const float*)d_in[7];  const float* sq2 = (const float*)d_in[8];  const float* bq2 = (const float*)d_in[9];
    const float* Wk1 = (const float*)d_in[10]; const float* sk1 = (const float*)d_in[11]; const float* bk1 = (const float*)d_in[12];
    const float* Wk2 = (const float*)d_in[13]; const float* sk2 = (const float*)d_in[14]; const float* bk2 = (const float*)d_in[15];
    const float* Wv  = (const float*)d_in[16]; const float* sv  = (const float*)d_in[17]; const float* bv  = (const float*)d_in[18];
    const float* Wo  = (const float*)d_in[19]; const float* so  = (const float*)d_in[20]; const float* bo  = (const float*)d_in[21];
    const float* Wb  = (const float*)d_in[22]; const float* sb  = (const float*)d_in[23]; const float* bb  = (const float*)d_in[24];

    char* ws = (char*)d_ws;
    bf16*   qt   = (bf16*)(ws);                        // [B][HW][C] bf16 : 16 MB
    bf16*   kbuf = (bf16*)(ws + (16u << 20));          // [B][K][C]  bf16 : 1 MB
    bf16*   vbuf = (bf16*)(ws + (17u << 20));          // [B][C][K]  bf16 : 1 MB
    char*   wbase = ws + (18u << 20);
    __bf16* Wq1p = (__bf16*)(wbase);
    __bf16* Wq2p = (__bf16*)(wbase + (32u << 10));
    __bf16* Wop  = (__bf16*)(wbase + (64u << 10));
    __bf16* Wbp  = (__bf16*)(wbase + (96u << 10));     // 128 KB
    float* outp = (float*)d_out;

    prep_kernel<<<1504, 256, 0, stream>>>(
        query, key, val,
        Wq1, sq1, Wq2, sq2, Wo, so, Wb, sb,
        Wk1, sk1, bk1, Wk2, sk2, bk2, Wv, sv, bv,
        qt, kbuf, vbuf, Wq1p, Wq2p, Wop, Wbp);
    mega_kernel<<<dim3(HW_ / 128, B_), 256, 0, stream>>>(
        qt, kbuf, vbuf, mask,
        Wq1p, bq1, Wq2p, bq2, Wop, bo, Wbp, bb, outp);
}

// Round 3
// 221.325 us; speedup vs baseline: 1.0469x; 1.0450x over previous
//
#include <hip/hip_runtime.h>
#include <hip/hip_bf16.h>

#define B_    4
#define C_    128
#define HW_   16384
#define K_    1024
// softmax runs in log2 domain: fold 128^-0.5 * log2(e) into the QK epilogue FMA
#define SC2_  0.12751734f
#define NEGL_ (-1.4427e7f)        // NEG * log2(e)
#define DTHR_ 8.0f                // defer-max threshold (log2 units): p <= 2^8

using bf16 = __hip_bfloat16;
typedef __bf16 b8v __attribute__((ext_vector_type(8)));
typedef __bf16 b4v __attribute__((ext_vector_type(4)));
typedef __bf16 b2v __attribute__((ext_vector_type(2)));
typedef float  f4v __attribute__((ext_vector_type(4)));

__device__ __forceinline__ b8v ldb8(const void* p) { return *(const b8v*)p; }
__device__ __forceinline__ b4v ldb4(const void* p) { return *(const b4v*)p; }

#define XSTRIDE 272   // 256 B row + 16 pad (b128 frag reads at bank floor)
#define KSTRIDE 272
#define VSTRIDE 136   // R0-proven V layout: 128 B row + 8 pad, ldb4-pair reads

// weight row (f32) -> bf16 fragment with BN scale folded, inline
__device__ __forceinline__ b8v ldw8(const float* wp, float sc) {
    const float4 a = *(const float4*)wp;
    const float4 c = *(const float4*)(wp + 4);
    b8v r;
    r[0] = (__bf16)(a.x * sc); r[1] = (__bf16)(a.y * sc);
    r[2] = (__bf16)(a.z * sc); r[3] = (__bf16)(a.w * sc);
    r[4] = (__bf16)(c.x * sc); r[5] = (__bf16)(c.y * sc);
    r[6] = (__bf16)(c.z * sc); r[7] = (__bf16)(c.w * sc);
    return r;
}

// ---------------------------------------------------------------------------
// prep: merged prep1 + kvproj (unchanged, proven R2).
//   blk [0,32)       : self-contained k/v projection blocks -> kbuf, vbuf
//   blk [32,1056)    : query transpose  f32 [b][c][p] -> bf16 qt [b][p][c]
//   blk [1056,1504)  : mega weight prep (Wq1,Wq2,Wo,Wb)
// ---------------------------------------------------------------------------
__global__ __launch_bounds__(256, 2) void prep_kernel(
    const float* __restrict__ query, const float* __restrict__ key, const float* __restrict__ val,
    const float* __restrict__ Wq1, const float* __restrict__ sq1,
    const float* __restrict__ Wq2, const float* __restrict__ sq2,
    const float* __restrict__ Wo,  const float* __restrict__ so,
    const float* __restrict__ Wb,  const float* __restrict__ sb,
    const float* __restrict__ Wk1, const float* __restrict__ sk1, const float* __restrict__ bk1,
    const float* __restrict__ Wk2, const float* __restrict__ sk2, const float* __restrict__ bk2,
    const float* __restrict__ Wv,  const float* __restrict__ sv_, const float* __restrict__ bv,
    bf16* __restrict__ qt, bf16* __restrict__ kbuf, bf16* __restrict__ vbuf,
    __bf16* __restrict__ Wq1p, __bf16* __restrict__ Wq2p,
    __bf16* __restrict__ Wop,  __bf16* __restrict__ Wbp)
{
    __shared__ __align__(16) char SM[69632];
    const int blk = blockIdx.x, t = threadIdx.x;

    if (blk < 32) {
        // ================= fused k/v projection =================
        const int b = blk >> 3, n0 = (blk & 7) * 128;
        const int w = t >> 6, lane = t & 63;
        const int pl = lane & 15, quad = lane >> 4;
        const int ob = 32 * w;
        const int plT = t & 63, cg = t >> 6;
        char*    Xs  = SM;                       // bf16 [128 pos][XSTRIDE]
        __bf16*  Ys  = (__bf16*)(SM + 34816);    // bf16 [128][136]
        float*   Tmp = (float*)(SM + 34816);     // f32 [64][129] (aliases Ys)

        auto transpose_in = [&](const float* src) {
#pragma unroll
            for (int h = 0; h < 2; ++h) {
                const int p0 = n0 + h * 64;
#pragma unroll 4
                for (int i2 = 0; i2 < 32; ++i2) {
                    const int c = cg * 32 + i2;
                    Tmp[plT * 129 + c] = src[(size_t)(b * 128 + c) * K_ + p0 + plT];
                }
                __syncthreads();
#pragma unroll 4
                for (int it = 0; it < 16; ++it) {
                    const int p = it * 4 + cg;
                    b2v pk2;
                    pk2[0] = (__bf16)Tmp[p * 129 + 2 * plT];
                    pk2[1] = (__bf16)Tmp[p * 129 + 2 * plT + 1];
                    *(b2v*)(Xs + (h * 64 + p) * XSTRIDE + 4 * plT) = pk2;
                }
                __syncthreads();
            }
        };

        // ---- K projection (2 layers) ----
        transpose_in(key);
        b8v W1f[2][4], W2f[2][4];
#pragma unroll
        for (int mt = 0; mt < 2; ++mt)
#pragma unroll
            for (int s = 0; s < 4; ++s) {
                const int row = ob + mt * 16 + pl;
                W1f[mt][s] = ldw8(Wk1 + row * 128 + s * 32 + quad * 8, sk1[row]);
                W2f[mt][s] = ldw8(Wk2 + row * 128 + s * 32 + quad * 8, sk2[row]);
            }
        {
            f4v acc[2][8];
#pragma unroll
            for (int mt = 0; mt < 2; ++mt)
#pragma unroll
                for (int nt = 0; nt < 8; ++nt) acc[mt][nt] = (f4v){0.f, 0.f, 0.f, 0.f};
#pragma unroll
            for (int s = 0; s < 4; ++s) {
                b8v Bf[8];
#pragma unroll
                for (int nt = 0; nt < 8; ++nt)
                    Bf[nt] = ldb8(Xs + (nt * 16 + pl) * XSTRIDE + s * 64 + quad * 16);
#pragma unroll
                for (int mt = 0; mt < 2; ++mt)
#pragma unroll
                    for (int nt = 0; nt < 8; ++nt)
                        acc[mt][nt] = __builtin_amdgcn_mfma_f32_16x16x32_bf16(W1f[mt][s], Bf[nt], acc[mt][nt], 0, 0, 0);
            }
#pragma unroll
            for (int mt = 0; mt < 2; ++mt) {
                const float4 s4 = *(const float4*)(bk1 + ob + mt * 16 + quad * 4);
                const float shf[4] = {s4.x, s4.y, s4.z, s4.w};
#pragma unroll
                for (int nt = 0; nt < 8; ++nt) {
                    b4v y;
#pragma unroll
                    for (int r = 0; r < 4; ++r) y[r] = (__bf16)fmaxf(acc[mt][nt][r] + shf[r], 0.f);
                    *(b4v*)&Ys[(nt * 16 + pl) * 136 + ob + mt * 16 + quad * 4] = y;
                }
            }
        }
        __syncthreads();
        {
            f4v acc2[2][8];
#pragma unroll
            for (int mt = 0; mt < 2; ++mt)
#pragma unroll
                for (int nt = 0; nt < 8; ++nt) acc2[mt][nt] = (f4v){0.f, 0.f, 0.f, 0.f};
#pragma unroll
            for (int s = 0; s < 4; ++s) {
                b8v Bf[8];
#pragma unroll
                for (int nt = 0; nt < 8; ++nt)
                    Bf[nt] = *(const b8v*)&Ys[(nt * 16 + pl) * 136 + s * 32 + quad * 8];
#pragma unroll
                for (int mt = 0; mt < 2; ++mt)
#pragma unroll
                    for (int nt = 0; nt < 8; ++nt)
                        acc2[mt][nt] = __builtin_amdgcn_mfma_f32_16x16x32_bf16(W2f[mt][s], Bf[nt], acc2[mt][nt], 0, 0, 0);
            }
            bf16* kdst = kbuf + ((size_t)b * K_ + n0) * 128;
#pragma unroll
            for (int mt = 0; mt < 2; ++mt) {
                const float4 s4 = *(const float4*)(bk2 + ob + mt * 16 + quad * 4);
                const float shf[4] = {s4.x, s4.y, s4.z, s4.w};
#pragma unroll
                for (int nt = 0; nt < 8; ++nt) {
                    b4v y;
#pragma unroll
                    for (int r = 0; r < 4; ++r) y[r] = (__bf16)fmaxf(acc2[mt][nt][r] + shf[r], 0.f);
                    *(b4v*)(kdst + (size_t)(nt * 16 + pl) * 128 + ob + mt * 16 + quad * 4) = y;
                }
            }
        }
        __syncthreads();   // Ys reads done before val-transpose reuses Tmp

        // ---- V projection (1 layer) ----
        transpose_in(val);
        b8v Wvf[2][4];
#pragma unroll
        for (int mt = 0; mt < 2; ++mt)
#pragma unroll
            for (int s = 0; s < 4; ++s) {
                const int row = ob + mt * 16 + pl;
                Wvf[mt][s] = ldw8(Wv + row * 128 + s * 32 + quad * 8, sv_[row]);
            }
        {
            f4v acc[2][8];
#pragma unroll
            for (int mt = 0; mt < 2; ++mt)
#pragma unroll
                for (int nt = 0; nt < 8; ++nt) acc[mt][nt] = (f4v){0.f, 0.f, 0.f, 0.f};
#pragma unroll
            for (int s = 0; s < 4; ++s) {
                b8v Bf[8];
#pragma unroll
                for (int nt = 0; nt < 8; ++nt)
                    Bf[nt] = ldb8(Xs + (nt * 16 + pl) * XSTRIDE + s * 64 + quad * 16);
#pragma unroll
                for (int mt = 0; mt < 2; ++mt)
#pragma unroll
                    for (int nt = 0; nt < 8; ++nt)
                        acc[mt][nt] = __builtin_amdgcn_mfma_f32_16x16x32_bf16(Wvf[mt][s], Bf[nt], acc[mt][nt], 0, 0, 0);
            }
            bf16* vdst = vbuf + (size_t)b * 128 * K_;
#pragma unroll
            for (int mt = 0; mt < 2; ++mt) {
                const float4 s4 = *(const float4*)(bv + ob + mt * 16 + quad * 4);
                const float shf[4] = {s4.x, s4.y, s4.z, s4.w};
#pragma unroll
                for (int nt = 0; nt < 8; ++nt)
#pragma unroll
                    for (int r = 0; r < 4; ++r)
                        vdst[(size_t)(ob + mt * 16 + quad * 4 + r) * K_ + n0 + nt * 16 + pl]
                            = __float2bfloat16(fmaxf(acc[mt][nt][r] + shf[r], 0.f));
            }
        }
    } else if (blk < 1056) {
        // ================= query transpose =================
        float* Xs2 = (float*)SM;
        const int i = blk - 32;
        const int b = i >> 8, p0 = (i & 255) * 64;
        const int pl = t & 63, cg = t >> 6;
#pragma unroll 4
        for (int i2 = 0; i2 < 32; ++i2) {
            const int c = cg * 32 + i2;
            Xs2[pl * 129 + c] = query[(size_t)(b * 128 + c) * HW_ + p0 + pl];
        }
        __syncthreads();
#pragma unroll 4
        for (int it = 0; it < 16; ++it) {
            const int p = it * 4 + cg;
            b2v pk2;
            pk2[0] = (__bf16)Xs2[p * 129 + 2 * pl];
            pk2[1] = (__bf16)Xs2[p * 129 + 2 * pl + 1];
            *(b2v*)(qt + ((size_t)b * HW_ + p0 + p) * 128 + 2 * pl) = pk2;
        }
    } else {
        // ================= mega weight prep =================
        const int idx = (blk - 1056) * 256 + t;
        if (idx < 16384)      { Wq1p[idx] = (__bf16)(Wq1[idx] * sq1[idx >> 7]); }
        else if (idx < 32768) { const int i2 = idx - 16384; Wq2p[i2] = (__bf16)(Wq2[i2] * sq2[i2 >> 7]); }
        else if (idx < 49152) { const int i2 = idx - 32768; Wop[i2]  = (__bf16)(Wo[i2]  * so[i2 >> 7]); }
        else                  { const int i2 = idx - 49152; Wbp[i2]  = (__bf16)(Wb[i2]  * sb[i2 >> 8]); }
    }
}

// ---------------------------------------------------------------------------
// mega: 512 threads / 8 waves per 128-query block (1 q-tile per wave).
// VGPR <=128 via __launch_bounds__(512,4) -> 4 waves/SIMD (2 blocks/CU).
// Same proven loop structure: single K/V buffer, lgkm-only barriers,
// log2 softmax with deferred rescale, setprio around MFMA clusters.
// LDS 69632 (2 blocks/CU). grid (HW/128, B).
// ---------------------------------------------------------------------------
__global__ __launch_bounds__(512, 4) void mega_kernel(
    const bf16* __restrict__ qt, const bf16* __restrict__ kbuf, const bf16* __restrict__ vbuf,
    const int* __restrict__ mask,
    const __bf16* __restrict__ Wq1p, const float* __restrict__ bq1,
    const __bf16* __restrict__ Wq2p, const float* __restrict__ bq2,
    const __bf16* __restrict__ Wop,  const float* __restrict__ bo,
    const __bf16* __restrict__ Wbp,  const float* __restrict__ bb,
    float* __restrict__ out)
{
    __shared__ __align__(16) char S[69632];

    const int t = threadIdx.x, w = t >> 6, lane = t & 63;
    const int pl = lane & 15, quad = lane >> 4;
    const int n0 = blockIdx.x * 128;
    const int b  = blockIdx.y;
    const int ob = 16 * w;                     // 16-channel slice per wave

    char*   RA  = S;
    __bf16* RAh = (__bf16*)S;
    __bf16* RBh = (__bf16*)(S + 34816);
    char* xl = RA + (t >> 4) * XSTRIDE + (t & 15) * 16;

    // ================= phase 1: q projection (into LDS) =================
    {
        const char* qg = (const char*)(qt + ((size_t)b * HW_ + n0) * 128) + t * 16;
#pragma unroll
        for (int i = 0; i < 4; ++i)
            *(float4*)(xl + i * 32 * XSTRIDE) = *(const float4*)(qg + i * 8192);
    }
    {
        b8v W1f[4], W2f[4];
#pragma unroll
        for (int s = 0; s < 4; ++s) {
            W1f[s] = ldb8(Wq1p + (ob + pl) * 128 + s * 32 + quad * 8);
            W2f[s] = ldb8(Wq2p + (ob + pl) * 128 + s * 32 + quad * 8);
        }
        __syncthreads();                       // sync1: q-tile in RA

        f4v a1[8];
#pragma unroll
        for (int nt = 0; nt < 8; ++nt) a1[nt] = (f4v){0.f, 0.f, 0.f, 0.f};
#pragma unroll
        for (int s = 0; s < 4; ++s) {
            b8v Bf[8];
#pragma unroll
            for (int nt = 0; nt < 8; ++nt)
                Bf[nt] = ldb8(RA + (nt * 16 + pl) * XSTRIDE + s * 64 + quad * 16);
#pragma unroll
            for (int nt = 0; nt < 8; ++nt)
                a1[nt] = __builtin_amdgcn_mfma_f32_16x16x32_bf16(W1f[s], Bf[nt], a1[nt], 0, 0, 0);
        }
        {
            const float4 s4 = *(const float4*)(bq1 + ob + quad * 4);
            const float shf[4] = {s4.x, s4.y, s4.z, s4.w};
#pragma unroll
            for (int nt = 0; nt < 8; ++nt) {
                b4v y;
#pragma unroll
                for (int r = 0; r < 4; ++r) y[r] = (__bf16)fmaxf(a1[nt][r] + shf[r], 0.f);
                *(b4v*)&RBh[(nt * 16 + pl) * 136 + ob + quad * 4] = y;
            }
        }
        __syncthreads();                       // sync2: y1 in RB, RA reads done

        f4v a2[8];
#pragma unroll
        for (int nt = 0; nt < 8; ++nt) a2[nt] = (f4v){0.f, 0.f, 0.f, 0.f};
#pragma unroll
        for (int s = 0; s < 4; ++s) {
            b8v Bf[8];
#pragma unroll
            for (int nt = 0; nt < 8; ++nt)
                Bf[nt] = *(const b8v*)&RBh[(nt * 16 + pl) * 136 + s * 32 + quad * 8];
#pragma unroll
            for (int nt = 0; nt < 8; ++nt)
                a2[nt] = __builtin_amdgcn_mfma_f32_16x16x32_bf16(W2f[s], Bf[nt], a2[nt], 0, 0, 0);
        }
        {
            const float4 s4 = *(const float4*)(bq2 + ob + quad * 4);
            const float shf[4] = {s4.x, s4.y, s4.z, s4.w};
#pragma unroll
            for (int nt = 0; nt < 8; ++nt) {
                b4v y;
#pragma unroll
                for (int r = 0; r < 4; ++r) y[r] = (__bf16)fmaxf(a2[nt][r] + shf[r], 0.f);
                *(b4v*)&RAh[(nt * 16 + pl) * 136 + ob + quad * 4] = y;
            }
        }
        __syncthreads();                       // sync3: q[pos][c] in RA
    }

    // q fragments: wave w owns queries w*16..w*16+15 (1 tile)
    b8v qf[4];
#pragma unroll
    for (int s = 0; s < 4; ++s)
        qf[s] = ldb8(RA + (w * 16 + pl) * XSTRIDE + s * 64 + quad * 16);
    __syncthreads();                           // sync4: qf read, RA free

    // ================= phase 2: attention =================
    float* bias = (float*)S;                   // 4096 B
    char* ktile = S + 4096;                    // 64*272 = 17408 B
    char* vtile = S + 34816;                   // 128*136 = 17408 B

    for (int i2 = t; i2 < K_; i2 += 512)
        bias[i2] = (mask[b * K_ + i2] != 0) ? 0.f : NEGL_;

    const bf16* kpt = kbuf + (size_t)b * K_ * 128;
    const bf16* vpt = vbuf + (size_t)b * 128 * K_;
    const char* kg = (const char*)kpt + t * 16;
    const char* vg = (const char*)(vpt + (size_t)(t >> 3) * K_) + (t & 7) * 16;
    char* kl = ktile + (t >> 4) * KSTRIDE + (t & 15) * 16;
    char* vl = vtile + (t >> 3) * VSTRIDE + (t & 7) * 16;

    float4 k_r0 = *(const float4*)(kg);
    float4 k_r1 = *(const float4*)(kg + 8192);
    float4 v_r0 = *(const float4*)(vg);
    float4 v_r1 = *(const float4*)(vg + 131072);

    f4v ac[8];
#pragma unroll
    for (int i = 0; i < 8; ++i) ac[i] = (f4v){0.f, 0.f, 0.f, 0.f};
    float mrun = -3.0e38f, lrun = 0.f;

    // lgkm-only barrier: LDS ops drained, global prefetch stays in flight.
#define RAW_BARRIER()                                                 \
    __builtin_amdgcn_sched_barrier(0);                                \
    asm volatile("s_waitcnt lgkmcnt(0)" ::: "memory");                \
    __builtin_amdgcn_s_barrier();                                     \
    __builtin_amdgcn_sched_barrier(0);

    for (int chunk = 0; chunk < 16; ++chunk) {
        const int k0 = chunk * 64;

        *(float4*)(kl)                = k_r0;
        *(float4*)(kl + 32 * KSTRIDE) = k_r1;
        *(float4*)(vl)                = v_r0;
        *(float4*)(vl + 64 * VSTRIDE) = v_r1;
        RAW_BARRIER()                          // tile visible; no vmcnt drain

        if (chunk < 15) {
            const char* kgn = kg + (chunk + 1) * 16384;
            const char* vgn = vg + (chunk + 1) * 128;
            k_r0 = *(const float4*)(kgn);
            k_r1 = *(const float4*)(kgn + 8192);
            v_r0 = *(const float4*)(vgn);
            v_r1 = *(const float4*)(vgn + 131072);
        }

        // ---- GEMM1: log2-domain scores for this wave's 16 queries
        f4v sv[4];
        __builtin_amdgcn_s_setprio(1);
#pragma unroll
        for (int kt = 0; kt < 4; ++kt) {
            f4v a = (f4v){0.f, 0.f, 0.f, 0.f};
            const char* krow = ktile + (kt * 16 + pl) * KSTRIDE + quad * 16;
#pragma unroll
            for (int s = 0; s < 4; ++s)
                a = __builtin_amdgcn_mfma_f32_16x16x32_bf16(ldb8(krow + s * 64), qf[s], a, 0, 0, 0);
            const float4 b4 = *(const float4*)&bias[k0 + kt * 16 + quad * 4];
            const float bb4[4] = {b4.x, b4.y, b4.z, b4.w};
#pragma unroll
            for (int r = 0; r < 4; ++r) sv[kt][r] = a[r] * SC2_ + bb4[r];
        }
        __builtin_amdgcn_s_setprio(0);

        // ---- online softmax (deferred rescale, T13)
        float ml = sv[0][0];
#pragma unroll
        for (int kt = 0; kt < 4; ++kt)
#pragma unroll
            for (int r = 0; r < 4; ++r) ml = fmaxf(ml, sv[kt][r]);
        ml = fmaxf(ml, __shfl_xor(ml, 16, 64));
        ml = fmaxf(ml, __shfl_xor(ml, 32, 64));

        if (__any(ml > mrun + DTHR_)) {
            const float mn = fmaxf(mrun, ml);
            const float al = exp2f(mrun - mn);
            lrun *= al; mrun = mn;
            float ar[4];
#pragma unroll
            for (int r = 0; r < 4; ++r) ar[r] = __shfl(al, quad * 4 + r, 64);
#pragma unroll
            for (int ct = 0; ct < 8; ++ct)
#pragma unroll
                for (int r = 0; r < 4; ++r) ac[ct][r] *= ar[r];
        }

        b4v pk[4];
        float rs = 0.f;
#pragma unroll
        for (int kt = 0; kt < 4; ++kt)
#pragma unroll
            for (int r = 0; r < 4; ++r) {
                const float p = exp2f(sv[kt][r] - mrun); rs += p; pk[kt][r] = (__bf16)p;
            }
        rs += __shfl_xor(rs, 16, 64); rs += __shfl_xor(rs, 32, 64);
        lrun += rs;

        // ---- GEMM2
        const b8v A0 = __builtin_shufflevector(pk[0], pk[1], 0, 1, 2, 3, 4, 5, 6, 7);
        const b8v A1 = __builtin_shufflevector(pk[2], pk[3], 0, 1, 2, 3, 4, 5, 6, 7);
        __builtin_amdgcn_s_setprio(1);
#pragma unroll
        for (int ct = 0; ct < 8; ++ct) {
            const char* vrow = vtile + (ct * 16 + pl) * VSTRIDE + quad * 8;
            const b8v B0 = __builtin_shufflevector(ldb4(vrow),      ldb4(vrow + 32), 0, 1, 2, 3, 4, 5, 6, 7);
            const b8v B1 = __builtin_shufflevector(ldb4(vrow + 64), ldb4(vrow + 96), 0, 1, 2, 3, 4, 5, 6, 7);
            ac[ct] = __builtin_amdgcn_mfma_f32_16x16x32_bf16(A0, B0, ac[ct], 0, 0, 0);
            ac[ct] = __builtin_amdgcn_mfma_f32_16x16x32_bf16(A1, B1, ac[ct], 0, 0, 0);
        }
        __builtin_amdgcn_s_setprio(0);

        RAW_BARRIER()                          // reads drained; next writes safe
    }
#undef RAW_BARRIER

    // ---- epilogue: normalized ctx -> RA [pos][c] bf16
    {
        float inv[4];
#pragma unroll
        for (int r = 0; r < 4; ++r) inv[r] = 1.f / __shfl(lrun, quad * 4 + r, 64);
#pragma unroll
        for (int ct = 0; ct < 8; ++ct)
#pragma unroll
            for (int r = 0; r < 4; ++r)
                RAh[(w * 16 + quad * 4 + r) * 136 + ct * 16 + pl] = (__bf16)(ac[ct][r] * inv[r]);
    }
    __syncthreads();                           // sync5: ctx in RA

    // ================= phase 3: final =================
    b8v Wof[4];
#pragma unroll
    for (int s = 0; s < 4; ++s)
        Wof[s] = ldb8(Wop + (ob + pl) * 128 + s * 32 + quad * 8);

    const char* qg2 = (const char*)(qt + ((size_t)b * HW_ + n0) * 128) + t * 16;
    float4 q_s0 = *(const float4*)(qg2);
    float4 q_s1 = *(const float4*)(qg2 + 8192);
    float4 q_s2 = *(const float4*)(qg2 + 16384);
    float4 q_s3 = *(const float4*)(qg2 + 24576);

    {
        f4v f1[8];
#pragma unroll
        for (int nt = 0; nt < 8; ++nt) f1[nt] = (f4v){0.f, 0.f, 0.f, 0.f};
#pragma unroll
        for (int s = 0; s < 4; ++s) {
            b8v Bf[8];
#pragma unroll
            for (int nt = 0; nt < 8; ++nt)
                Bf[nt] = ldb8(RA + (nt * 16 + pl) * XSTRIDE + s * 64 + quad * 16);
#pragma unroll
            for (int nt = 0; nt < 8; ++nt)
                f1[nt] = __builtin_amdgcn_mfma_f32_16x16x32_bf16(Wof[s], Bf[nt], f1[nt], 0, 0, 0);
        }
        {
            const float4 s4 = *(const float4*)(bo + ob + quad * 4);
            const float shf[4] = {s4.x, s4.y, s4.z, s4.w};
#pragma unroll
            for (int nt = 0; nt < 8; ++nt) {
                b4v y;
#pragma unroll
                for (int r = 0; r < 4; ++r) y[r] = (__bf16)fmaxf(f1[nt][r] + shf[r], 0.f);
                *(b4v*)&RBh[(nt * 16 + pl) * 136 + ob + quad * 4] = y;
            }
        }
    }
    __syncthreads();                           // sync6: ctx2 in RB, RA reads done

    *(float4*)(xl)                 = q_s0;
    *(float4*)(xl + 32 * XSTRIDE)  = q_s1;
    *(float4*)(xl + 64 * XSTRIDE)  = q_s2;
    *(float4*)(xl + 96 * XSTRIDE)  = q_s3;
    __syncthreads();                           // sync7: qt in RA

    {
        f4v f2[2][8];
#pragma unroll
        for (int mt = 0; mt < 2; ++mt)
#pragma unroll
            for (int nt = 0; nt < 8; ++nt) f2[mt][nt] = (f4v){0.f, 0.f, 0.f, 0.f};
#pragma unroll
        for (int ks = 0; ks < 8; ++ks) {
            b8v Af[2];
#pragma unroll
            for (int mt = 0; mt < 2; ++mt)
                Af[mt] = ldb8(Wbp + (size_t)(32 * w + mt * 16 + pl) * 256 + ks * 32 + quad * 8);
            b8v Bf[8];
            if (ks < 4) {
#pragma unroll
                for (int nt = 0; nt < 8; ++nt)
                    Bf[nt] = *(const b8v*)&RBh[(nt * 16 + pl) * 136 + ks * 32 + quad * 8];
            } else {
#pragma unroll
                for (int nt = 0; nt < 8; ++nt)
                    Bf[nt] = ldb8(RA + (nt * 16 + pl) * XSTRIDE + (ks - 4) * 64 + quad * 16);
            }
#pragma unroll
            for (int mt = 0; mt < 2; ++mt)
#pragma unroll
                for (int nt = 0; nt < 8; ++nt)
                    f2[mt][nt] = __builtin_amdgcn_mfma_f32_16x16x32_bf16(Af[mt], Bf[nt], f2[mt][nt], 0, 0, 0);
        }
#pragma unroll
        for (int mt = 0; mt < 2; ++mt) {
            const float4 s4 = *(const float4*)(bb + 32 * w + mt * 16 + quad * 4);
            const float shf[4] = {s4.x, s4.y, s4.z, s4.w};
#pragma unroll
            for (int nt = 0; nt < 8; ++nt)
#pragma unroll
                for (int r = 0; r < 4; ++r)
                    out[(size_t)(b * 256 + 32 * w + mt * 16 + quad * 4 + r) * HW_ + n0 + nt * 16 + pl]
                        = fmaxf(f2[mt][nt][r] + shf[r], 0.f);
        }
    }
}

// ---------------------------------------------------------------------------
extern "C" void kernel_launch(void* const* d_in, const int* in_sizes, int n_in,
                              void* d_out, int out_size, void* d_ws, size_t ws_size,
                              hipStream_t stream)
{
    const float* query = (const float*)d_in[0];
    const float* key   = (const float*)d_in[1];
    const float* val   = (const float*)d_in[2];
    const int*   mask  = (const int*)  d_in[3];
    const float* Wq1 = (const float*)d_in[4];  const float* sq1 = (const float*)d_in[5];  const float* bq1 = (const float*)d_in[6];
    const float* Wq2 = (const float*)d_in[7];  const float* sq2 = (const float*)d_in[8];  const float* bq2 = (const float*)d_in[9];
    const float* Wk1 = (const float*)d_in[10]; const float* sk1 = (const float*)d_in[11]; const float* bk1 = (const float*)d_in[12];
    const float* Wk2 = (const float*)d_in[13]; const float* sk2 = (const float*)d_in[14]; const float* bk2 = (const float*)d_in[15];
    const float* Wv  = (const float*)d_in[16]; const float* sv  = (const float*)d_in[17]; const float* bv  = (const float*)d_in[18];
    const float* Wo  = (const float*)d_in[19]; const float* so  = (const float*)d_in[20]; const float* bo  = (const float*)d_in[21];
    const float* Wb  = (const float*)d_in[22]; const float* sb  = (const float*)d_in[23]; const float* bb  = (const float*)d_in[24];

    char* ws = (char*)d_ws;
    bf16*   qt   = (bf16*)(ws);                        // [B][HW][C] bf16 : 16 MB
    bf16*   kbuf = (bf16*)(ws + (16u << 20));          // [B][K][C]  bf16 : 1 MB
    bf16*   vbuf = (bf16*)(ws + (17u << 20));          // [B][C][K]  bf16 : 1 MB
    char*   wbase = ws + (18u << 20);
    __bf16* Wq1p = (__bf16*)(wbase);
    __bf16* Wq2p = (__bf16*)(wbase + (32u << 10));
    __bf16* Wop  = (__bf16*)(wbase + (64u << 10));
    __bf16* Wbp  = (__bf16*)(wbase + (96u << 10));     // 128 KB
    float* outp = (float*)d_out;

    prep_kernel<<<1504, 256, 0, stream>>>(
        query, key, val,
        Wq1, sq1, Wq2, sq2, Wo, so, Wb, sb,
        Wk1, sk1, bk1, Wk2, sk2, bk2, Wv, sv, bv,
        qt, kbuf, vbuf, Wq1p, Wq2p, Wop, Wbp);
    mega_kernel<<<dim3(HW_ / 128, B_), 512, 0, stream>>>(
        qt, kbuf, vbuf, mask,
        Wq1p, bq1, Wq2p, bq2, Wop, bo, Wbp, bb, outp);
}